// Round 5
// baseline (398.052 us; speedup 1.0000x reference)
//
#include <hip/hip_runtime.h>
#include <hip/hip_fp16.h>

#define NN 50000
#define NE 800000
#define NG 500
#define IND 128
#define HD 96
#define OD 64

#define SCAN_CHUNK 2048
#define SCAN_BLOCKS ((NN + SCAN_CHUNK - 1) / SCAN_CHUNK)  // 25

// ---------------- CSR build ----------------

__global__ void zero_k(int* __restrict__ cnt, int* __restrict__ fill,
                       int* __restrict__ gcnt, float* __restrict__ P) {
  int i = blockIdx.x * 256 + threadIdx.x;
  if (i < NN) { cnt[i] = 0; fill[i] = 0; }
  if (i < NG) gcnt[i] = 0;
  if (i < 3 * NG * HD) P[i] = 0.f;
}

__global__ void hist_k(const int* __restrict__ dst, int* __restrict__ cnt) {
  int i = blockIdx.x * 256 + threadIdx.x;
  if (i < NE) atomicAdd(&cnt[dst[i]], 1);
}

__global__ void gcnt_k(const int* __restrict__ batch, int* __restrict__ gcnt) {
  int i = blockIdx.x * 256 + threadIdx.x;
  if (i < NN) atomicAdd(&gcnt[batch[i]], 1);
}

// phase 1: per-block partial sums over 2048-elem chunks; also dinv = rsqrt(deg+1)
__global__ __launch_bounds__(256) void scan_part_k(const int* __restrict__ cnt,
                                                   int* __restrict__ bsum,
                                                   float* __restrict__ dinv) {
  __shared__ int ts[256];
  const int tid = threadIdx.x;
  const int base = blockIdx.x * SCAN_CHUNK + tid * 8;
  int s = 0;
#pragma unroll
  for (int j = 0; j < 8; j++) {
    int idx = base + j;
    if (idx < NN) {
      int c = cnt[idx];
      s += c;
      dinv[idx] = rsqrtf((float)(c + 1));
    }
  }
  ts[tid] = s;
  __syncthreads();
  for (int off = 128; off > 0; off >>= 1) {
    if (tid < off) ts[tid] += ts[tid + off];
    __syncthreads();
  }
  if (tid == 0) bsum[blockIdx.x] = ts[0];
}

// phase 2: one wave scans the 25 block sums -> exclusive boff; row_ptr[NN]=NE
__global__ __launch_bounds__(64) void scan_top_k(const int* __restrict__ bsum,
                                                 int* __restrict__ boff,
                                                 int* __restrict__ row_ptr) {
  int tid = threadIdx.x;
  int v = (tid < SCAN_BLOCKS) ? bsum[tid] : 0;
  for (int off = 1; off < 64; off <<= 1) {
    int u = __shfl_up(v, off);
    if (tid >= off) v += u;
  }
  if (tid < SCAN_BLOCKS) boff[tid] = v - bsum[tid];  // exclusive
  if (tid == 0) row_ptr[NN] = NE;
}

// phase 3: per-block local exclusive scan + block offset -> row_ptr
__global__ __launch_bounds__(256) void scan_fin_k(const int* __restrict__ cnt,
                                                  const int* __restrict__ boff,
                                                  int* __restrict__ row_ptr) {
  __shared__ int ts[256];
  const int tid = threadIdx.x;
  const int base = blockIdx.x * SCAN_CHUNK + tid * 8;
  int v[8];
  int s = 0;
#pragma unroll
  for (int j = 0; j < 8; j++) {
    int idx = base + j;
    v[j] = (idx < NN) ? cnt[idx] : 0;
    s += v[j];
  }
  ts[tid] = s;
  __syncthreads();
  for (int off = 1; off < 256; off <<= 1) {
    int t = (tid >= off) ? ts[tid - off] : 0;
    __syncthreads();
    ts[tid] += t;
    __syncthreads();
  }
  int run = ((tid == 0) ? 0 : ts[tid - 1]) + boff[blockIdx.x];
#pragma unroll
  for (int j = 0; j < 8; j++) {
    int idx = base + j;
    if (idx < NN) row_ptr[idx] = run;
    run += v[j];
  }
}

__global__ void fill_k(const int* __restrict__ src, const int* __restrict__ dst,
                       const int* __restrict__ row_ptr, int* __restrict__ fill,
                       int* __restrict__ col) {
  int i = blockIdx.x * 256 + threadIdx.x;
  if (i < NE) {
    int d = dst[i];
    int slot = row_ptr[d] + atomicAdd(&fill[d], 1);
    col[slot] = src[i];
  }
}

// ---------------- g = fp16((h @ W) * dinv[:,None])  (8x8 register-tiled) ----------------
// BM=128 rows, BN=96 (all cols), BK=32. 192 threads = 16 rowg x 12 colg.
template <int K>
__global__ __launch_bounds__(192) void gemm_scale_k(const float* __restrict__ h,
                                                    const float* __restrict__ W,
                                                    const float* __restrict__ dinv,
                                                    __half* __restrict__ g) {
  __shared__ __attribute__((aligned(16))) float hsT[32][132];  // stride 528B
  __shared__ __attribute__((aligned(16))) float ws[32][100];   // stride 400B
  const int tid = threadIdx.x;
  const int colg = tid % 12;
  const int rowg = tid / 12;
  const int row0 = blockIdx.x * 128;

  float acc[8][8];
#pragma unroll
  for (int i = 0; i < 8; i++)
#pragma unroll
    for (int j = 0; j < 8; j++) acc[i][j] = 0.f;

  for (int k0 = 0; k0 < K; k0 += 32) {
    for (int lin = tid; lin < 1024; lin += 192) {
      int r = lin >> 3, q = lin & 7;
      int grow = row0 + r;
      float4 v = make_float4(0.f, 0.f, 0.f, 0.f);
      if (grow < NN) v = *reinterpret_cast<const float4*>(&h[(long)grow * K + k0 + 4 * q]);
      hsT[4 * q + 0][r] = v.x;
      hsT[4 * q + 1][r] = v.y;
      hsT[4 * q + 2][r] = v.z;
      hsT[4 * q + 3][r] = v.w;
    }
    for (int lin = tid; lin < 768; lin += 192) {
      int kk = lin / 24, c4 = lin - kk * 24;
      *reinterpret_cast<float4*>(&ws[kk][4 * c4]) =
          *reinterpret_cast<const float4*>(&W[(long)(k0 + kk) * HD + 4 * c4]);
    }
    __syncthreads();
#pragma unroll 8
    for (int k = 0; k < 32; k++) {
      float4 a0 = *reinterpret_cast<const float4*>(&hsT[k][8 * rowg]);
      float4 a1 = *reinterpret_cast<const float4*>(&hsT[k][8 * rowg + 4]);
      float4 w0 = *reinterpret_cast<const float4*>(&ws[k][8 * colg]);
      float4 w1 = *reinterpret_cast<const float4*>(&ws[k][8 * colg + 4]);
      float a[8] = {a0.x, a0.y, a0.z, a0.w, a1.x, a1.y, a1.z, a1.w};
      float w[8] = {w0.x, w0.y, w0.z, w0.w, w1.x, w1.y, w1.z, w1.w};
#pragma unroll
      for (int i = 0; i < 8; i++)
#pragma unroll
        for (int j = 0; j < 8; j++) acc[i][j] = fmaf(a[i], w[j], acc[i][j]);
    }
    __syncthreads();
  }
  // epilogue: scale by dinv[row], pack 8 fp32 -> 4 half2, one 16B store per row
#pragma unroll
  for (int i = 0; i < 8; i++) {
    int row = row0 + 8 * rowg + i;
    if (row < NN) {
      float dv = dinv[row];
      __half2 hh[4];
#pragma unroll
      for (int q = 0; q < 4; q++)
        hh[q] = __floats2half2_rn(acc[i][2 * q] * dv, acc[i][2 * q + 1] * dv);
      *reinterpret_cast<float4*>(&g[(long)row * HD + 8 * colg]) =
          *reinterpret_cast<float4*>(hh);
    }
  }
}

// ---------------- CSR gather (fp16 g) + relu + fused graph pooling ----------------
// one wave per node; lane l<48 owns col-pair 2l (one half2 = 4B); lanes 48-63
// mirror lane 0's load (same cache line, no extra traffic, no divergence).
// 16-edge batches keep 16 independent loads in flight.
template <bool WRITE_H>
__global__ __launch_bounds__(256) void gather_k(const __half* __restrict__ g,
                                                const int* __restrict__ row_ptr,
                                                const int* __restrict__ col,
                                                const float* __restrict__ dinv,
                                                const float* __restrict__ bias,
                                                const int* __restrict__ batch,
                                                float* __restrict__ hout,
                                                float* __restrict__ P) {
  int d = blockIdx.x * 4 + (threadIdx.x >> 6);
  int lane = threadIdx.x & 63;
  if (d >= NN) return;
  const int cl = (lane < 48) ? lane : 0;
  const __half2* gd = reinterpret_cast<const __half2*>(g + (long)d * HD);
  float2 fs = __half22float2(gd[cl]);
  float accx = fs.x, accy = fs.y;  // self-loop contribution
  int e = row_ptr[d];
  const int end = row_ptr[d + 1];
  while (e < end) {
    int cnt = end - e; if (cnt > 64) cnt = 64;
    int cid = (lane < cnt) ? col[e + lane] : 0;
    int j = 0;
    for (; j + 16 <= cnt; j += 16) {
      const __half2* p0  = reinterpret_cast<const __half2*>(g + (long)__shfl(cid, j + 0)  * HD);
      const __half2* p1  = reinterpret_cast<const __half2*>(g + (long)__shfl(cid, j + 1)  * HD);
      const __half2* p2  = reinterpret_cast<const __half2*>(g + (long)__shfl(cid, j + 2)  * HD);
      const __half2* p3  = reinterpret_cast<const __half2*>(g + (long)__shfl(cid, j + 3)  * HD);
      const __half2* p4  = reinterpret_cast<const __half2*>(g + (long)__shfl(cid, j + 4)  * HD);
      const __half2* p5  = reinterpret_cast<const __half2*>(g + (long)__shfl(cid, j + 5)  * HD);
      const __half2* p6  = reinterpret_cast<const __half2*>(g + (long)__shfl(cid, j + 6)  * HD);
      const __half2* p7  = reinterpret_cast<const __half2*>(g + (long)__shfl(cid, j + 7)  * HD);
      const __half2* p8  = reinterpret_cast<const __half2*>(g + (long)__shfl(cid, j + 8)  * HD);
      const __half2* p9  = reinterpret_cast<const __half2*>(g + (long)__shfl(cid, j + 9)  * HD);
      const __half2* p10 = reinterpret_cast<const __half2*>(g + (long)__shfl(cid, j + 10) * HD);
      const __half2* p11 = reinterpret_cast<const __half2*>(g + (long)__shfl(cid, j + 11) * HD);
      const __half2* p12 = reinterpret_cast<const __half2*>(g + (long)__shfl(cid, j + 12) * HD);
      const __half2* p13 = reinterpret_cast<const __half2*>(g + (long)__shfl(cid, j + 13) * HD);
      const __half2* p14 = reinterpret_cast<const __half2*>(g + (long)__shfl(cid, j + 14) * HD);
      const __half2* p15 = reinterpret_cast<const __half2*>(g + (long)__shfl(cid, j + 15) * HD);
      __half2 v0 = p0[cl],  v1 = p1[cl],  v2 = p2[cl],  v3 = p3[cl];
      __half2 v4 = p4[cl],  v5 = p5[cl],  v6 = p6[cl],  v7 = p7[cl];
      __half2 v8 = p8[cl],  v9 = p9[cl],  v10 = p10[cl], v11 = p11[cl];
      __half2 v12 = p12[cl], v13 = p13[cl], v14 = p14[cl], v15 = p15[cl];
      float2 f;
      f = __half22float2(v0);  accx += f.x; accy += f.y;
      f = __half22float2(v1);  accx += f.x; accy += f.y;
      f = __half22float2(v2);  accx += f.x; accy += f.y;
      f = __half22float2(v3);  accx += f.x; accy += f.y;
      f = __half22float2(v4);  accx += f.x; accy += f.y;
      f = __half22float2(v5);  accx += f.x; accy += f.y;
      f = __half22float2(v6);  accx += f.x; accy += f.y;
      f = __half22float2(v7);  accx += f.x; accy += f.y;
      f = __half22float2(v8);  accx += f.x; accy += f.y;
      f = __half22float2(v9);  accx += f.x; accy += f.y;
      f = __half22float2(v10); accx += f.x; accy += f.y;
      f = __half22float2(v11); accx += f.x; accy += f.y;
      f = __half22float2(v12); accx += f.x; accy += f.y;
      f = __half22float2(v13); accx += f.x; accy += f.y;
      f = __half22float2(v14); accx += f.x; accy += f.y;
      f = __half22float2(v15); accx += f.x; accy += f.y;
    }
    for (; j < cnt; j++) {
      const __half2* p = reinterpret_cast<const __half2*>(g + (long)__shfl(cid, j) * HD);
      float2 f = __half22float2(p[cl]);
      accx += f.x; accy += f.y;
    }
    e += 64;
  }
  if (lane < 48) {
    float dv = dinv[d];
    int gr = batch[d];
    float v0 = fmaxf(fmaf(accx, dv, bias[2 * lane]), 0.f);
    float v1 = fmaxf(fmaf(accy, dv, bias[2 * lane + 1]), 0.f);
    if (WRITE_H) {
      float2 o = make_float2(v0, v1);
      *reinterpret_cast<float2*>(&hout[(long)d * HD + 2 * lane]) = o;
    }
    atomicAdd(&P[gr * HD + 2 * lane], v0);
    atomicAdd(&P[gr * HD + 2 * lane + 1], v1);
  }
}

// ---------------- tiny dense tail: JK-proj on pooled sums + MLP ----------------

__global__ void emb_k(const float* __restrict__ P, const int* __restrict__ gcnt,
                      const float* __restrict__ Wjk, const float* __restrict__ bjk,
                      float* __restrict__ emb) {
  int idx = blockIdx.x * 256 + threadIdx.x;
  if (idx >= NG * HD) return;
  int gr = idx / HD, c = idx - gr * HD;
  const float* p1 = P + (long)gr * HD;
  const float* p2 = p1 + (long)NG * HD;
  const float* p3 = p2 + (long)NG * HD;
  float acc = (float)gcnt[gr] * bjk[c];
  for (int k = 0; k < HD; k++) {
    acc = fmaf(p1[k], Wjk[k * HD + c], acc);
    acc = fmaf(p2[k], Wjk[(HD + k) * HD + c], acc);
    acc = fmaf(p3[k], Wjk[(2 * HD + k) * HD + c], acc);
  }
  emb[idx] = acc;
}

__global__ void mlp1_k(const float* __restrict__ emb, const float* __restrict__ W,
                       const float* __restrict__ b, float* __restrict__ hid) {
  int idx = blockIdx.x * 256 + threadIdx.x;
  if (idx >= NG * HD) return;
  int gr = idx / HD, c = idx - gr * HD;
  const float* e = emb + (long)gr * HD;
  float acc = b[c];
  for (int k = 0; k < HD; k++) acc = fmaf(e[k], W[k * HD + c], acc);
  hid[idx] = fmaxf(acc, 0.f);
}

__global__ void mlp2_k(const float* __restrict__ hid, const float* __restrict__ W,
                       const float* __restrict__ b, float* __restrict__ out) {
  int idx = blockIdx.x * 256 + threadIdx.x;
  if (idx >= NG * OD) return;
  int gr = idx / OD, c = idx - gr * OD;
  const float* h = hid + (long)gr * HD;
  float acc = b[c];
  for (int k = 0; k < HD; k++) acc = fmaf(h[k], W[k * OD + c], acc);
  out[idx] = acc;
}

// ---------------- launch ----------------

extern "C" void kernel_launch(void* const* d_in, const int* in_sizes, int n_in,
                              void* d_out, int out_size, void* d_ws, size_t ws_size,
                              hipStream_t stream) {
  const float* x = (const float*)d_in[0];
  const int* ei = (const int*)d_in[1];
  const int* batch = (const int*)d_in[2];
  const float* W0 = (const float*)d_in[3];  const float* b0 = (const float*)d_in[4];
  const float* W1 = (const float*)d_in[5];  const float* b1 = (const float*)d_in[6];
  const float* W2 = (const float*)d_in[7];  const float* b2 = (const float*)d_in[8];
  const float* Wjk = (const float*)d_in[9]; const float* bjk = (const float*)d_in[10];
  const float* Wm1 = (const float*)d_in[11]; const float* bm1 = (const float*)d_in[12];
  const float* Wm2 = (const float*)d_in[13]; const float* bm2 = (const float*)d_in[14];
  const int* srcp = ei;
  const int* dstp = ei + NE;

  char* wp = (char*)d_ws;
  size_t off = 0;
  auto alloc = [&](size_t bytes) -> void* {
    void* p = wp + off;
    off += bytes;
    off = (off + 255) & ~(size_t)255;
    return p;
  };
  int* cnt   = (int*)alloc((size_t)NN * 4);
  int* rowp  = (int*)alloc((size_t)(NN + 1) * 4);
  int* fill  = (int*)alloc((size_t)NN * 4);
  int* colb  = (int*)alloc((size_t)NE * 4);
  float* dinv = (float*)alloc((size_t)NN * 4);
  int* gcnt  = (int*)alloc((size_t)NG * 4);
  int* bsum  = (int*)alloc((size_t)SCAN_BLOCKS * 4);
  int* boff  = (int*)alloc((size_t)SCAN_BLOCKS * 4);
  __half* g  = (__half*)alloc((size_t)NN * HD * 2);
  float* hA  = (float*)alloc((size_t)NN * HD * 4);
  float* hB  = (float*)alloc((size_t)NN * HD * 4);
  float* P   = (float*)alloc((size_t)3 * NG * HD * 4);
  float* emb = (float*)alloc((size_t)NG * HD * 4);
  float* hid = (float*)alloc((size_t)NG * HD * 4);

  // zero accumulators (must happen every call — harness does not re-poison)
  zero_k<<<(3 * NG * HD + 255) / 256, 256, 0, stream>>>(cnt, fill, gcnt, P);

  // CSR build + degrees (multi-block scan)
  hist_k<<<(NE + 255) / 256, 256, 0, stream>>>(dstp, cnt);
  gcnt_k<<<(NN + 255) / 256, 256, 0, stream>>>(batch, gcnt);
  scan_part_k<<<SCAN_BLOCKS, 256, 0, stream>>>(cnt, bsum, dinv);
  scan_top_k<<<1, 64, 0, stream>>>(bsum, boff, rowp);
  scan_fin_k<<<SCAN_BLOCKS, 256, 0, stream>>>(cnt, boff, rowp);
  fill_k<<<(NE + 255) / 256, 256, 0, stream>>>(srcp, dstp, rowp, fill, colb);

  const int gemm_grid = (NN + 127) / 128;
  // layer 1: x[50000,128] -> hA
  gemm_scale_k<IND><<<gemm_grid, 192, 0, stream>>>(x, W0, dinv, g);
  gather_k<true><<<(NN + 3) / 4, 256, 0, stream>>>(g, rowp, colb, dinv, b0, batch, hA, P);
  // layer 2: hA -> hB
  gemm_scale_k<HD><<<gemm_grid, 192, 0, stream>>>(hA, W1, dinv, g);
  gather_k<true><<<(NN + 3) / 4, 256, 0, stream>>>(g, rowp, colb, dinv, b1, batch, hB, P + NG * HD);
  // layer 3: hB -> (pool only)
  gemm_scale_k<HD><<<gemm_grid, 192, 0, stream>>>(hB, W2, dinv, g);
  gather_k<false><<<(NN + 3) / 4, 256, 0, stream>>>(g, rowp, colb, dinv, b2, batch, hA, P + 2 * NG * HD);

  // JK cat + lin on pooled sums (linearity of pooling), then MLP head
  emb_k<<<(NG * HD + 255) / 256, 256, 0, stream>>>(P, gcnt, Wjk, bjk, emb);
  mlp1_k<<<(NG * HD + 255) / 256, 256, 0, stream>>>(emb, Wm1, bm1, hid);
  mlp2_k<<<(NG * OD + 255) / 256, 256, 0, stream>>>(hid, Wm2, bm2, (float*)d_out);
}

// Round 6
// 312.014 us; speedup vs baseline: 1.2758x; 1.2758x over previous
//
#include <hip/hip_runtime.h>
#include <hip/hip_fp16.h>

#define NN 50000
#define NE 800000
#define NG 500
#define IND 128
#define HD 96
#define OD 64

#define SCAN_CHUNK 2048
#define SCAN_BLOCKS ((NN + SCAN_CHUNK - 1) / SCAN_CHUNK)  // 25

// ---------------- CSR build ----------------

__global__ void zero_k(int* __restrict__ cnt, int* __restrict__ fill) {
  int i = blockIdx.x * 256 + threadIdx.x;
  if (i < NN) { cnt[i] = 0; fill[i] = 0; }
}

__global__ void hist_k(const int* __restrict__ dst, int* __restrict__ cnt) {
  int i = blockIdx.x * 256 + threadIdx.x;
  if (i < NE) atomicAdd(&cnt[dst[i]], 1);
}

// graph start offsets from sorted batch (boundary detection, no atomics)
__global__ void gstart_k(const int* __restrict__ batch, int* __restrict__ gstart) {
  int n = blockIdx.x * 256 + threadIdx.x;
  if (n >= NN) return;
  if (n == 0) {
    for (int g = 0; g <= batch[0]; g++) gstart[g] = 0;
    for (int g = batch[NN - 1] + 1; g <= NG; g++) gstart[g] = NN;
  } else {
    int b0 = batch[n - 1], b1 = batch[n];
    for (int g = b0 + 1; g <= b1; g++) gstart[g] = n;
  }
}

// phase 1: per-block partial sums over 2048-elem chunks; also dinv = rsqrt(deg+1)
__global__ __launch_bounds__(256) void scan_part_k(const int* __restrict__ cnt,
                                                   int* __restrict__ bsum,
                                                   float* __restrict__ dinv) {
  __shared__ int ts[256];
  const int tid = threadIdx.x;
  const int base = blockIdx.x * SCAN_CHUNK + tid * 8;
  int s = 0;
#pragma unroll
  for (int j = 0; j < 8; j++) {
    int idx = base + j;
    if (idx < NN) {
      int c = cnt[idx];
      s += c;
      dinv[idx] = rsqrtf((float)(c + 1));
    }
  }
  ts[tid] = s;
  __syncthreads();
  for (int off = 128; off > 0; off >>= 1) {
    if (tid < off) ts[tid] += ts[tid + off];
    __syncthreads();
  }
  if (tid == 0) bsum[blockIdx.x] = ts[0];
}

// phase 2: one wave scans the 25 block sums -> exclusive boff; row_ptr[NN]=NE
__global__ __launch_bounds__(64) void scan_top_k(const int* __restrict__ bsum,
                                                 int* __restrict__ boff,
                                                 int* __restrict__ row_ptr) {
  int tid = threadIdx.x;
  int v = (tid < SCAN_BLOCKS) ? bsum[tid] : 0;
  for (int off = 1; off < 64; off <<= 1) {
    int u = __shfl_up(v, off);
    if (tid >= off) v += u;
  }
  if (tid < SCAN_BLOCKS) boff[tid] = v - bsum[tid];  // exclusive
  if (tid == 0) row_ptr[NN] = NE;
}

// phase 3: per-block local exclusive scan + block offset -> row_ptr
__global__ __launch_bounds__(256) void scan_fin_k(const int* __restrict__ cnt,
                                                  const int* __restrict__ boff,
                                                  int* __restrict__ row_ptr) {
  __shared__ int ts[256];
  const int tid = threadIdx.x;
  const int base = blockIdx.x * SCAN_CHUNK + tid * 8;
  int v[8];
  int s = 0;
#pragma unroll
  for (int j = 0; j < 8; j++) {
    int idx = base + j;
    v[j] = (idx < NN) ? cnt[idx] : 0;
    s += v[j];
  }
  ts[tid] = s;
  __syncthreads();
  for (int off = 1; off < 256; off <<= 1) {
    int t = (tid >= off) ? ts[tid - off] : 0;
    __syncthreads();
    ts[tid] += t;
    __syncthreads();
  }
  int run = ((tid == 0) ? 0 : ts[tid - 1]) + boff[blockIdx.x];
#pragma unroll
  for (int j = 0; j < 8; j++) {
    int idx = base + j;
    if (idx < NN) row_ptr[idx] = run;
    run += v[j];
  }
}

// col stores BYTE offsets of source rows in g (src * HD * 2): no mul in gather
__global__ void fill_k(const int* __restrict__ src, const int* __restrict__ dst,
                       const int* __restrict__ row_ptr, int* __restrict__ fill,
                       int* __restrict__ col) {
  int i = blockIdx.x * 256 + threadIdx.x;
  if (i < NE) {
    int d = dst[i];
    int slot = row_ptr[d] + atomicAdd(&fill[d], 1);
    col[slot] = src[i] * (HD * 2);
  }
}

// ---------------- g = fp16((h @ W) * dinv[:,None])  (8x8 register-tiled) ----------------
// BM=128 rows, BN=96 (all cols), BK=32. 192 threads = 16 rowg x 12 colg.
template <int K>
__global__ __launch_bounds__(192) void gemm_scale_k(const float* __restrict__ h,
                                                    const float* __restrict__ W,
                                                    const float* __restrict__ dinv,
                                                    __half* __restrict__ g) {
  __shared__ __attribute__((aligned(16))) float hsT[32][132];  // stride 528B
  __shared__ __attribute__((aligned(16))) float ws[32][100];   // stride 400B
  const int tid = threadIdx.x;
  const int colg = tid % 12;
  const int rowg = tid / 12;
  const int row0 = blockIdx.x * 128;

  float acc[8][8];
#pragma unroll
  for (int i = 0; i < 8; i++)
#pragma unroll
    for (int j = 0; j < 8; j++) acc[i][j] = 0.f;

  for (int k0 = 0; k0 < K; k0 += 32) {
    for (int lin = tid; lin < 1024; lin += 192) {
      int r = lin >> 3, q = lin & 7;
      int grow = row0 + r;
      float4 v = make_float4(0.f, 0.f, 0.f, 0.f);
      if (grow < NN) v = *reinterpret_cast<const float4*>(&h[(long)grow * K + k0 + 4 * q]);
      hsT[4 * q + 0][r] = v.x;
      hsT[4 * q + 1][r] = v.y;
      hsT[4 * q + 2][r] = v.z;
      hsT[4 * q + 3][r] = v.w;
    }
    for (int lin = tid; lin < 768; lin += 192) {
      int kk = lin / 24, c4 = lin - kk * 24;
      *reinterpret_cast<float4*>(&ws[kk][4 * c4]) =
          *reinterpret_cast<const float4*>(&W[(long)(k0 + kk) * HD + 4 * c4]);
    }
    __syncthreads();
#pragma unroll 8
    for (int k = 0; k < 32; k++) {
      float4 a0 = *reinterpret_cast<const float4*>(&hsT[k][8 * rowg]);
      float4 a1 = *reinterpret_cast<const float4*>(&hsT[k][8 * rowg + 4]);
      float4 w0 = *reinterpret_cast<const float4*>(&ws[k][8 * colg]);
      float4 w1 = *reinterpret_cast<const float4*>(&ws[k][8 * colg + 4]);
      float a[8] = {a0.x, a0.y, a0.z, a0.w, a1.x, a1.y, a1.z, a1.w};
      float w[8] = {w0.x, w0.y, w0.z, w0.w, w1.x, w1.y, w1.z, w1.w};
#pragma unroll
      for (int i = 0; i < 8; i++)
#pragma unroll
        for (int j = 0; j < 8; j++) acc[i][j] = fmaf(a[i], w[j], acc[i][j]);
    }
    __syncthreads();
  }
#pragma unroll
  for (int i = 0; i < 8; i++) {
    int row = row0 + 8 * rowg + i;
    if (row < NN) {
      float dv = dinv[row];
      __half2 hh[4];
#pragma unroll
      for (int q = 0; q < 4; q++)
        hh[q] = __floats2half2_rn(acc[i][2 * q] * dv, acc[i][2 * q + 1] * dv);
      *reinterpret_cast<float4*>(&g[(long)row * HD + 8 * colg]) =
          *reinterpret_cast<float4*>(hh);
    }
  }
}

// ---------------- CSR gather (fp16 g) + relu -> hout (NO pooling atomics) ----------------
// one wave per node; lane l<48 owns col-pair 2l (one half2 = 4B); lanes 48-63
// mirror lane 0 (same cache line). col[] holds byte offsets. 16/8-edge batches.
__global__ __launch_bounds__(256) void gather_k(const __half* __restrict__ g,
                                                const int* __restrict__ row_ptr,
                                                const int* __restrict__ col,
                                                const float* __restrict__ dinv,
                                                const float* __restrict__ bias,
                                                float* __restrict__ hout) {
  int d = blockIdx.x * 4 + (threadIdx.x >> 6);
  int lane = threadIdx.x & 63;
  if (d >= NN) return;
  const int cl = (lane < 48) ? lane : 0;
  const char* gb = reinterpret_cast<const char*>(g);
  const __half2* gd = reinterpret_cast<const __half2*>(gb + (long)d * (HD * 2));
  float2 fs = __half22float2(gd[cl]);
  float accx = fs.x, accy = fs.y;  // self-loop contribution
  int e = row_ptr[d];
  const int end = row_ptr[d + 1];
  while (e < end) {
    int cnt = end - e; if (cnt > 64) cnt = 64;
    int cid = (lane < cnt) ? col[e + lane] : 0;
    int j = 0;
    for (; j + 16 <= cnt; j += 16) {
      const __half2* p0  = reinterpret_cast<const __half2*>(gb + (long)__shfl(cid, j + 0));
      const __half2* p1  = reinterpret_cast<const __half2*>(gb + (long)__shfl(cid, j + 1));
      const __half2* p2  = reinterpret_cast<const __half2*>(gb + (long)__shfl(cid, j + 2));
      const __half2* p3  = reinterpret_cast<const __half2*>(gb + (long)__shfl(cid, j + 3));
      const __half2* p4  = reinterpret_cast<const __half2*>(gb + (long)__shfl(cid, j + 4));
      const __half2* p5  = reinterpret_cast<const __half2*>(gb + (long)__shfl(cid, j + 5));
      const __half2* p6  = reinterpret_cast<const __half2*>(gb + (long)__shfl(cid, j + 6));
      const __half2* p7  = reinterpret_cast<const __half2*>(gb + (long)__shfl(cid, j + 7));
      const __half2* p8  = reinterpret_cast<const __half2*>(gb + (long)__shfl(cid, j + 8));
      const __half2* p9  = reinterpret_cast<const __half2*>(gb + (long)__shfl(cid, j + 9));
      const __half2* p10 = reinterpret_cast<const __half2*>(gb + (long)__shfl(cid, j + 10));
      const __half2* p11 = reinterpret_cast<const __half2*>(gb + (long)__shfl(cid, j + 11));
      const __half2* p12 = reinterpret_cast<const __half2*>(gb + (long)__shfl(cid, j + 12));
      const __half2* p13 = reinterpret_cast<const __half2*>(gb + (long)__shfl(cid, j + 13));
      const __half2* p14 = reinterpret_cast<const __half2*>(gb + (long)__shfl(cid, j + 14));
      const __half2* p15 = reinterpret_cast<const __half2*>(gb + (long)__shfl(cid, j + 15));
      __half2 v0 = p0[cl],  v1 = p1[cl],  v2 = p2[cl],  v3 = p3[cl];
      __half2 v4 = p4[cl],  v5 = p5[cl],  v6 = p6[cl],  v7 = p7[cl];
      __half2 v8 = p8[cl],  v9 = p9[cl],  v10 = p10[cl], v11 = p11[cl];
      __half2 v12 = p12[cl], v13 = p13[cl], v14 = p14[cl], v15 = p15[cl];
      float2 f;
      f = __half22float2(v0);  accx += f.x; accy += f.y;
      f = __half22float2(v1);  accx += f.x; accy += f.y;
      f = __half22float2(v2);  accx += f.x; accy += f.y;
      f = __half22float2(v3);  accx += f.x; accy += f.y;
      f = __half22float2(v4);  accx += f.x; accy += f.y;
      f = __half22float2(v5);  accx += f.x; accy += f.y;
      f = __half22float2(v6);  accx += f.x; accy += f.y;
      f = __half22float2(v7);  accx += f.x; accy += f.y;
      f = __half22float2(v8);  accx += f.x; accy += f.y;
      f = __half22float2(v9);  accx += f.x; accy += f.y;
      f = __half22float2(v10); accx += f.x; accy += f.y;
      f = __half22float2(v11); accx += f.x; accy += f.y;
      f = __half22float2(v12); accx += f.x; accy += f.y;
      f = __half22float2(v13); accx += f.x; accy += f.y;
      f = __half22float2(v14); accx += f.x; accy += f.y;
      f = __half22float2(v15); accx += f.x; accy += f.y;
    }
    for (; j + 8 <= cnt; j += 8) {
      const __half2* q0 = reinterpret_cast<const __half2*>(gb + (long)__shfl(cid, j + 0));
      const __half2* q1 = reinterpret_cast<const __half2*>(gb + (long)__shfl(cid, j + 1));
      const __half2* q2 = reinterpret_cast<const __half2*>(gb + (long)__shfl(cid, j + 2));
      const __half2* q3 = reinterpret_cast<const __half2*>(gb + (long)__shfl(cid, j + 3));
      const __half2* q4 = reinterpret_cast<const __half2*>(gb + (long)__shfl(cid, j + 4));
      const __half2* q5 = reinterpret_cast<const __half2*>(gb + (long)__shfl(cid, j + 5));
      const __half2* q6 = reinterpret_cast<const __half2*>(gb + (long)__shfl(cid, j + 6));
      const __half2* q7 = reinterpret_cast<const __half2*>(gb + (long)__shfl(cid, j + 7));
      __half2 v0 = q0[cl], v1 = q1[cl], v2 = q2[cl], v3 = q3[cl];
      __half2 v4 = q4[cl], v5 = q5[cl], v6 = q6[cl], v7 = q7[cl];
      float2 f;
      f = __half22float2(v0); accx += f.x; accy += f.y;
      f = __half22float2(v1); accx += f.x; accy += f.y;
      f = __half22float2(v2); accx += f.x; accy += f.y;
      f = __half22float2(v3); accx += f.x; accy += f.y;
      f = __half22float2(v4); accx += f.x; accy += f.y;
      f = __half22float2(v5); accx += f.x; accy += f.y;
      f = __half22float2(v6); accx += f.x; accy += f.y;
      f = __half22float2(v7); accx += f.x; accy += f.y;
    }
    for (; j < cnt; j++) {
      const __half2* p = reinterpret_cast<const __half2*>(gb + (long)__shfl(cid, j));
      float2 f = __half22float2(p[cl]);
      accx += f.x; accy += f.y;
    }
    e += 64;
  }
  if (lane < 48) {
    float dv = dinv[d];
    float2 bb = *reinterpret_cast<const float2*>(&bias[2 * lane]);
    float v0 = fmaxf(fmaf(accx, dv, bb.x), 0.f);
    float v1 = fmaxf(fmaf(accy, dv, bb.y), 0.f);
    *reinterpret_cast<float2*>(&hout[(long)d * HD + 2 * lane]) = make_float2(v0, v1);
  }
}

// ---------------- pooling: one block per graph, contiguous rows, NO atomics ----------------
// 240 active threads = 24 float4-col-groups x 10 node-substreams; LDS reduce.
__global__ __launch_bounds__(256) void pool3_k(const float* __restrict__ hA,
                                               const float* __restrict__ hB,
                                               const float* __restrict__ hC,
                                               const int* __restrict__ gstart,
                                               float* __restrict__ P) {
  __shared__ float red[240][12];
  const int g = blockIdx.x;
  const int t = threadIdx.x;
  const int q = t % 24, s = t / 24;
  const int n0 = gstart[g], n1 = gstart[g + 1];
  if (t < 240) {
    float4 aA = make_float4(0.f, 0.f, 0.f, 0.f), aB = aA, aC = aA;
    for (int n = n0 + s; n < n1; n += 10) {
      float4 v;
      v = *reinterpret_cast<const float4*>(&hA[(long)n * HD + 4 * q]);
      aA.x += v.x; aA.y += v.y; aA.z += v.z; aA.w += v.w;
      v = *reinterpret_cast<const float4*>(&hB[(long)n * HD + 4 * q]);
      aB.x += v.x; aB.y += v.y; aB.z += v.z; aB.w += v.w;
      v = *reinterpret_cast<const float4*>(&hC[(long)n * HD + 4 * q]);
      aC.x += v.x; aC.y += v.y; aC.z += v.z; aC.w += v.w;
    }
    red[t][0] = aA.x; red[t][1] = aA.y; red[t][2]  = aA.z; red[t][3]  = aA.w;
    red[t][4] = aB.x; red[t][5] = aB.y; red[t][6]  = aB.z; red[t][7]  = aB.w;
    red[t][8] = aC.x; red[t][9] = aC.y; red[t][10] = aC.z; red[t][11] = aC.w;
  }
  __syncthreads();
  if (t < 24) {
    float sum[12];
#pragma unroll
    for (int c = 0; c < 12; c++) sum[c] = 0.f;
    for (int ss = 0; ss < 10; ss++)
#pragma unroll
      for (int c = 0; c < 12; c++) sum[c] += red[ss * 24 + t][c];
#pragma unroll
    for (int k = 0; k < 4; k++) {
      P[0 * NG * HD + g * HD + 4 * t + k] = sum[k];
      P[1 * NG * HD + g * HD + 4 * t + k] = sum[4 + k];
      P[2 * NG * HD + g * HD + 4 * t + k] = sum[8 + k];
    }
  }
}

// ---------------- tiny dense tail: JK-proj on pooled sums + MLP ----------------

__global__ void emb_k(const float* __restrict__ P, const int* __restrict__ gstart,
                      const float* __restrict__ Wjk, const float* __restrict__ bjk,
                      float* __restrict__ emb) {
  int idx = blockIdx.x * 256 + threadIdx.x;
  if (idx >= NG * HD) return;
  int gr = idx / HD, c = idx - gr * HD;
  const float* p1 = P + (long)gr * HD;
  const float* p2 = p1 + (long)NG * HD;
  const float* p3 = p2 + (long)NG * HD;
  float acc = (float)(gstart[gr + 1] - gstart[gr]) * bjk[c];
  for (int k = 0; k < HD; k++) {
    acc = fmaf(p1[k], Wjk[k * HD + c], acc);
    acc = fmaf(p2[k], Wjk[(HD + k) * HD + c], acc);
    acc = fmaf(p3[k], Wjk[(2 * HD + k) * HD + c], acc);
  }
  emb[idx] = acc;
}

__global__ void mlp1_k(const float* __restrict__ emb, const float* __restrict__ W,
                       const float* __restrict__ b, float* __restrict__ hid) {
  int idx = blockIdx.x * 256 + threadIdx.x;
  if (idx >= NG * HD) return;
  int gr = idx / HD, c = idx - gr * HD;
  const float* e = emb + (long)gr * HD;
  float acc = b[c];
  for (int k = 0; k < HD; k++) acc = fmaf(e[k], W[k * HD + c], acc);
  hid[idx] = fmaxf(acc, 0.f);
}

__global__ void mlp2_k(const float* __restrict__ hid, const float* __restrict__ W,
                       const float* __restrict__ b, float* __restrict__ out) {
  int idx = blockIdx.x * 256 + threadIdx.x;
  if (idx >= NG * OD) return;
  int gr = idx / OD, c = idx - gr * OD;
  const float* h = hid + (long)gr * HD;
  float acc = b[c];
  for (int k = 0; k < HD; k++) acc = fmaf(h[k], W[k * OD + c], acc);
  out[idx] = acc;
}

// ---------------- launch ----------------

extern "C" void kernel_launch(void* const* d_in, const int* in_sizes, int n_in,
                              void* d_out, int out_size, void* d_ws, size_t ws_size,
                              hipStream_t stream) {
  const float* x = (const float*)d_in[0];
  const int* ei = (const int*)d_in[1];
  const int* batch = (const int*)d_in[2];
  const float* W0 = (const float*)d_in[3];  const float* b0 = (const float*)d_in[4];
  const float* W1 = (const float*)d_in[5];  const float* b1 = (const float*)d_in[6];
  const float* W2 = (const float*)d_in[7];  const float* b2 = (const float*)d_in[8];
  const float* Wjk = (const float*)d_in[9]; const float* bjk = (const float*)d_in[10];
  const float* Wm1 = (const float*)d_in[11]; const float* bm1 = (const float*)d_in[12];
  const float* Wm2 = (const float*)d_in[13]; const float* bm2 = (const float*)d_in[14];
  const int* srcp = ei;
  const int* dstp = ei + NE;

  char* wp = (char*)d_ws;
  size_t off = 0;
  auto alloc = [&](size_t bytes) -> void* {
    void* p = wp + off;
    off += bytes;
    off = (off + 255) & ~(size_t)255;
    return p;
  };
  int* cnt    = (int*)alloc((size_t)NN * 4);
  int* rowp   = (int*)alloc((size_t)(NN + 1) * 4);
  int* fill   = (int*)alloc((size_t)NN * 4);
  int* colb   = (int*)alloc((size_t)NE * 4);
  float* dinv = (float*)alloc((size_t)NN * 4);
  int* gstart = (int*)alloc((size_t)(NG + 1) * 4);
  int* bsum   = (int*)alloc((size_t)SCAN_BLOCKS * 4);
  int* boff   = (int*)alloc((size_t)SCAN_BLOCKS * 4);
  __half* g   = (__half*)alloc((size_t)NN * HD * 2);
  float* hA   = (float*)alloc((size_t)NN * HD * 4);
  float* hB   = (float*)alloc((size_t)NN * HD * 4);
  float* hC   = (float*)alloc((size_t)NN * HD * 4);
  float* P    = (float*)alloc((size_t)3 * NG * HD * 4);
  float* emb  = (float*)alloc((size_t)NG * HD * 4);
  float* hid  = (float*)alloc((size_t)NG * HD * 4);

  // zero CSR counters (must happen every call — harness does not re-poison)
  zero_k<<<(NN + 255) / 256, 256, 0, stream>>>(cnt, fill);

  // CSR build + degrees + graph offsets
  hist_k<<<(NE + 255) / 256, 256, 0, stream>>>(dstp, cnt);
  gstart_k<<<(NN + 255) / 256, 256, 0, stream>>>(batch, gstart);
  scan_part_k<<<SCAN_BLOCKS, 256, 0, stream>>>(cnt, bsum, dinv);
  scan_top_k<<<1, 64, 0, stream>>>(bsum, boff, rowp);
  scan_fin_k<<<SCAN_BLOCKS, 256, 0, stream>>>(cnt, boff, rowp);
  fill_k<<<(NE + 255) / 256, 256, 0, stream>>>(srcp, dstp, rowp, fill, colb);

  const int gemm_grid = (NN + 127) / 128;
  const int gath_grid = (NN + 3) / 4;
  // layer 1: x[50000,128] -> hA
  gemm_scale_k<IND><<<gemm_grid, 192, 0, stream>>>(x, W0, dinv, g);
  gather_k<<<gath_grid, 256, 0, stream>>>(g, rowp, colb, dinv, b0, hA);
  // layer 2: hA -> hB
  gemm_scale_k<HD><<<gemm_grid, 192, 0, stream>>>(hA, W1, dinv, g);
  gather_k<<<gath_grid, 256, 0, stream>>>(g, rowp, colb, dinv, b1, hB);
  // layer 3: hB -> hC
  gemm_scale_k<HD><<<gemm_grid, 192, 0, stream>>>(hB, W2, dinv, g);
  gather_k<<<gath_grid, 256, 0, stream>>>(g, rowp, colb, dinv, b2, hC);

  // pooling (one block per graph, contiguous ranges, no atomics)
  pool3_k<<<NG, 256, 0, stream>>>(hA, hB, hC, gstart, P);

  // JK cat + lin on pooled sums (linearity of pooling), then MLP head
  emb_k<<<(NG * HD + 255) / 256, 256, 0, stream>>>(P, gstart, Wjk, bjk, emb);
  mlp1_k<<<(NG * HD + 255) / 256, 256, 0, stream>>>(emb, Wm1, bm1, hid);
  mlp2_k<<<(NG * OD + 255) / 256, 256, 0, stream>>>(hid, Wm2, bm2, (float*)d_out);
}

// Round 7
// 279.951 us; speedup vs baseline: 1.4219x; 1.1145x over previous
//
#include <hip/hip_runtime.h>
#include <hip/hip_fp16.h>

#define NN 50000
#define NE 800000
#define NG 500
#define IND 128
#define HD 96
#define OD 64

#define SCAN_CHUNK 2048
#define SCAN_BLOCKS ((NN + SCAN_CHUNK - 1) / SCAN_CHUNK)  // 25

// ---------------- CSR build ----------------

__global__ void zero_k(int* __restrict__ cnt) {
  int i = blockIdx.x * 256 + threadIdx.x;
  if (i < NN) cnt[i] = 0;
}

// histogram + within-node rank in one pass (8 edges/thread, independent chains)
__global__ void hist_k(const int* __restrict__ dst, int* __restrict__ cnt,
                       int* __restrict__ rank) {
  int i0 = (blockIdx.x * 256 + threadIdx.x) * 8;
  if (i0 + 8 <= NE) {
    int4 d0 = *reinterpret_cast<const int4*>(&dst[i0]);
    int4 d1 = *reinterpret_cast<const int4*>(&dst[i0 + 4]);
    int4 r0, r1;
    r0.x = atomicAdd(&cnt[d0.x], 1);
    r0.y = atomicAdd(&cnt[d0.y], 1);
    r0.z = atomicAdd(&cnt[d0.z], 1);
    r0.w = atomicAdd(&cnt[d0.w], 1);
    r1.x = atomicAdd(&cnt[d1.x], 1);
    r1.y = atomicAdd(&cnt[d1.y], 1);
    r1.z = atomicAdd(&cnt[d1.z], 1);
    r1.w = atomicAdd(&cnt[d1.w], 1);
    *reinterpret_cast<int4*>(&rank[i0]) = r0;
    *reinterpret_cast<int4*>(&rank[i0 + 4]) = r1;
  } else {
    for (int i = i0; i < NE; i++) rank[i] = atomicAdd(&cnt[dst[i]], 1);
  }
}

// graph start offsets from sorted batch (boundary detection, no atomics)
__global__ void gstart_k(const int* __restrict__ batch, int* __restrict__ gstart) {
  int n = blockIdx.x * 256 + threadIdx.x;
  if (n >= NN) return;
  if (n == 0) {
    for (int g = 0; g <= batch[0]; g++) gstart[g] = 0;
    for (int g = batch[NN - 1] + 1; g <= NG; g++) gstart[g] = NN;
  } else {
    int b0 = batch[n - 1], b1 = batch[n];
    for (int g = b0 + 1; g <= b1; g++) gstart[g] = n;
  }
}

// phase 1: per-block partial sums over 2048-elem chunks; also dinv = rsqrt(deg+1)
__global__ __launch_bounds__(256) void scan_part_k(const int* __restrict__ cnt,
                                                   int* __restrict__ bsum,
                                                   float* __restrict__ dinv) {
  __shared__ int ts[256];
  const int tid = threadIdx.x;
  const int base = blockIdx.x * SCAN_CHUNK + tid * 8;
  int s = 0;
#pragma unroll
  for (int j = 0; j < 8; j++) {
    int idx = base + j;
    if (idx < NN) {
      int c = cnt[idx];
      s += c;
      dinv[idx] = rsqrtf((float)(c + 1));
    }
  }
  ts[tid] = s;
  __syncthreads();
  for (int off = 128; off > 0; off >>= 1) {
    if (tid < off) ts[tid] += ts[tid + off];
    __syncthreads();
  }
  if (tid == 0) bsum[blockIdx.x] = ts[0];
}

// phase 2: one wave scans the 25 block sums -> exclusive boff; row_ptr[NN]=NE
__global__ __launch_bounds__(64) void scan_top_k(const int* __restrict__ bsum,
                                                 int* __restrict__ boff,
                                                 int* __restrict__ row_ptr) {
  int tid = threadIdx.x;
  int v = (tid < SCAN_BLOCKS) ? bsum[tid] : 0;
  for (int off = 1; off < 64; off <<= 1) {
    int u = __shfl_up(v, off);
    if (tid >= off) v += u;
  }
  if (tid < SCAN_BLOCKS) boff[tid] = v - bsum[tid];  // exclusive
  if (tid == 0) row_ptr[NN] = NE;
}

// phase 3: per-block local exclusive scan + block offset -> row_ptr
__global__ __launch_bounds__(256) void scan_fin_k(const int* __restrict__ cnt,
                                                  const int* __restrict__ boff,
                                                  int* __restrict__ row_ptr) {
  __shared__ int ts[256];
  const int tid = threadIdx.x;
  const int base = blockIdx.x * SCAN_CHUNK + tid * 8;
  int v[8];
  int s = 0;
#pragma unroll
  for (int j = 0; j < 8; j++) {
    int idx = base + j;
    v[j] = (idx < NN) ? cnt[idx] : 0;
    s += v[j];
  }
  ts[tid] = s;
  __syncthreads();
  for (int off = 1; off < 256; off <<= 1) {
    int t = (tid >= off) ? ts[tid - off] : 0;
    __syncthreads();
    ts[tid] += t;
    __syncthreads();
  }
  int run = ((tid == 0) ? 0 : ts[tid - 1]) + boff[blockIdx.x];
#pragma unroll
  for (int j = 0; j < 8; j++) {
    int idx = base + j;
    if (idx < NN) row_ptr[idx] = run;
    run += v[j];
  }
}

// atomic-free scatter: col[rowp[d]+rank] = src byte-offset (8 edges/thread)
__global__ void fill_k(const int* __restrict__ src, const int* __restrict__ dst,
                       const int* __restrict__ row_ptr, const int* __restrict__ rank,
                       int* __restrict__ col) {
  int i0 = (blockIdx.x * 256 + threadIdx.x) * 8;
  if (i0 + 8 <= NE) {
    int4 d0 = *reinterpret_cast<const int4*>(&dst[i0]);
    int4 d1 = *reinterpret_cast<const int4*>(&dst[i0 + 4]);
    int4 s0 = *reinterpret_cast<const int4*>(&src[i0]);
    int4 s1 = *reinterpret_cast<const int4*>(&src[i0 + 4]);
    int4 r0 = *reinterpret_cast<const int4*>(&rank[i0]);
    int4 r1 = *reinterpret_cast<const int4*>(&rank[i0 + 4]);
    int p0 = row_ptr[d0.x], p1 = row_ptr[d0.y], p2 = row_ptr[d0.z], p3 = row_ptr[d0.w];
    int p4 = row_ptr[d1.x], p5 = row_ptr[d1.y], p6 = row_ptr[d1.z], p7 = row_ptr[d1.w];
    col[p0 + r0.x] = s0.x * (HD * 2);
    col[p1 + r0.y] = s0.y * (HD * 2);
    col[p2 + r0.z] = s0.z * (HD * 2);
    col[p3 + r0.w] = s0.w * (HD * 2);
    col[p4 + r1.x] = s1.x * (HD * 2);
    col[p5 + r1.y] = s1.y * (HD * 2);
    col[p6 + r1.z] = s1.z * (HD * 2);
    col[p7 + r1.w] = s1.w * (HD * 2);
  } else {
    for (int i = i0; i < NE; i++)
      col[row_ptr[dst[i]] + rank[i]] = src[i] * (HD * 2);
  }
}

// ---------------- g = fp16((h @ W) * dinv[:,None])  (8x8 register-tiled) ----------------
// BM=128 rows, BN=96 (all cols), BK=32. 192 threads = 16 rowg x 12 colg.
template <int K>
__global__ __launch_bounds__(192) void gemm_scale_k(const float* __restrict__ h,
                                                    const float* __restrict__ W,
                                                    const float* __restrict__ dinv,
                                                    __half* __restrict__ g) {
  __shared__ __attribute__((aligned(16))) float hsT[32][132];  // stride 528B
  __shared__ __attribute__((aligned(16))) float ws[32][100];   // stride 400B
  const int tid = threadIdx.x;
  const int colg = tid % 12;
  const int rowg = tid / 12;
  const int row0 = blockIdx.x * 128;

  float acc[8][8];
#pragma unroll
  for (int i = 0; i < 8; i++)
#pragma unroll
    for (int j = 0; j < 8; j++) acc[i][j] = 0.f;

  for (int k0 = 0; k0 < K; k0 += 32) {
    for (int lin = tid; lin < 1024; lin += 192) {
      int r = lin >> 3, q = lin & 7;
      int grow = row0 + r;
      float4 v = make_float4(0.f, 0.f, 0.f, 0.f);
      if (grow < NN) v = *reinterpret_cast<const float4*>(&h[(long)grow * K + k0 + 4 * q]);
      hsT[4 * q + 0][r] = v.x;
      hsT[4 * q + 1][r] = v.y;
      hsT[4 * q + 2][r] = v.z;
      hsT[4 * q + 3][r] = v.w;
    }
    for (int lin = tid; lin < 768; lin += 192) {
      int kk = lin / 24, c4 = lin - kk * 24;
      *reinterpret_cast<float4*>(&ws[kk][4 * c4]) =
          *reinterpret_cast<const float4*>(&W[(long)(k0 + kk) * HD + 4 * c4]);
    }
    __syncthreads();
#pragma unroll 8
    for (int k = 0; k < 32; k++) {
      float4 a0 = *reinterpret_cast<const float4*>(&hsT[k][8 * rowg]);
      float4 a1 = *reinterpret_cast<const float4*>(&hsT[k][8 * rowg + 4]);
      float4 w0 = *reinterpret_cast<const float4*>(&ws[k][8 * colg]);
      float4 w1 = *reinterpret_cast<const float4*>(&ws[k][8 * colg + 4]);
      float a[8] = {a0.x, a0.y, a0.z, a0.w, a1.x, a1.y, a1.z, a1.w};
      float w[8] = {w0.x, w0.y, w0.z, w0.w, w1.x, w1.y, w1.z, w1.w};
#pragma unroll
      for (int i = 0; i < 8; i++)
#pragma unroll
        for (int j = 0; j < 8; j++) acc[i][j] = fmaf(a[i], w[j], acc[i][j]);
    }
    __syncthreads();
  }
#pragma unroll
  for (int i = 0; i < 8; i++) {
    int row = row0 + 8 * rowg + i;
    if (row < NN) {
      float dv = dinv[row];
      __half2 hh[4];
#pragma unroll
      for (int q = 0; q < 4; q++)
        hh[q] = __floats2half2_rn(acc[i][2 * q] * dv, acc[i][2 * q + 1] * dv);
      *reinterpret_cast<float4*>(&g[(long)row * HD + 8 * colg]) =
          *reinterpret_cast<float4*>(hh);
    }
  }
}

// ---------------- CSR gather (fp16 g) + relu -> hout ----------------
// one wave per node; lane l<48 owns col-pair 2l (one half2 = 4B); lanes 48-63
// mirror lane 0 (same cache line). col[] holds byte offsets. 16/8-edge batches.
__global__ __launch_bounds__(256) void gather_k(const __half* __restrict__ g,
                                                const int* __restrict__ row_ptr,
                                                const int* __restrict__ col,
                                                const float* __restrict__ dinv,
                                                const float* __restrict__ bias,
                                                float* __restrict__ hout) {
  int d = blockIdx.x * 4 + (threadIdx.x >> 6);
  int lane = threadIdx.x & 63;
  if (d >= NN) return;
  const int cl = (lane < 48) ? lane : 0;
  const char* gb = reinterpret_cast<const char*>(g);
  const __half2* gd = reinterpret_cast<const __half2*>(gb + (long)d * (HD * 2));
  float2 fs = __half22float2(gd[cl]);
  float accx = fs.x, accy = fs.y;  // self-loop contribution
  int e = row_ptr[d];
  const int end = row_ptr[d + 1];
  while (e < end) {
    int cnt = end - e; if (cnt > 64) cnt = 64;
    int cid = (lane < cnt) ? col[e + lane] : 0;
    int j = 0;
    for (; j + 16 <= cnt; j += 16) {
      const __half2* p0  = reinterpret_cast<const __half2*>(gb + (long)__shfl(cid, j + 0));
      const __half2* p1  = reinterpret_cast<const __half2*>(gb + (long)__shfl(cid, j + 1));
      const __half2* p2  = reinterpret_cast<const __half2*>(gb + (long)__shfl(cid, j + 2));
      const __half2* p3  = reinterpret_cast<const __half2*>(gb + (long)__shfl(cid, j + 3));
      const __half2* p4  = reinterpret_cast<const __half2*>(gb + (long)__shfl(cid, j + 4));
      const __half2* p5  = reinterpret_cast<const __half2*>(gb + (long)__shfl(cid, j + 5));
      const __half2* p6  = reinterpret_cast<const __half2*>(gb + (long)__shfl(cid, j + 6));
      const __half2* p7  = reinterpret_cast<const __half2*>(gb + (long)__shfl(cid, j + 7));
      const __half2* p8  = reinterpret_cast<const __half2*>(gb + (long)__shfl(cid, j + 8));
      const __half2* p9  = reinterpret_cast<const __half2*>(gb + (long)__shfl(cid, j + 9));
      const __half2* p10 = reinterpret_cast<const __half2*>(gb + (long)__shfl(cid, j + 10));
      const __half2* p11 = reinterpret_cast<const __half2*>(gb + (long)__shfl(cid, j + 11));
      const __half2* p12 = reinterpret_cast<const __half2*>(gb + (long)__shfl(cid, j + 12));
      const __half2* p13 = reinterpret_cast<const __half2*>(gb + (long)__shfl(cid, j + 13));
      const __half2* p14 = reinterpret_cast<const __half2*>(gb + (long)__shfl(cid, j + 14));
      const __half2* p15 = reinterpret_cast<const __half2*>(gb + (long)__shfl(cid, j + 15));
      __half2 v0 = p0[cl],  v1 = p1[cl],  v2 = p2[cl],  v3 = p3[cl];
      __half2 v4 = p4[cl],  v5 = p5[cl],  v6 = p6[cl],  v7 = p7[cl];
      __half2 v8 = p8[cl],  v9 = p9[cl],  v10 = p10[cl], v11 = p11[cl];
      __half2 v12 = p12[cl], v13 = p13[cl], v14 = p14[cl], v15 = p15[cl];
      float2 f;
      f = __half22float2(v0);  accx += f.x; accy += f.y;
      f = __half22float2(v1);  accx += f.x; accy += f.y;
      f = __half22float2(v2);  accx += f.x; accy += f.y;
      f = __half22float2(v3);  accx += f.x; accy += f.y;
      f = __half22float2(v4);  accx += f.x; accy += f.y;
      f = __half22float2(v5);  accx += f.x; accy += f.y;
      f = __half22float2(v6);  accx += f.x; accy += f.y;
      f = __half22float2(v7);  accx += f.x; accy += f.y;
      f = __half22float2(v8);  accx += f.x; accy += f.y;
      f = __half22float2(v9);  accx += f.x; accy += f.y;
      f = __half22float2(v10); accx += f.x; accy += f.y;
      f = __half22float2(v11); accx += f.x; accy += f.y;
      f = __half22float2(v12); accx += f.x; accy += f.y;
      f = __half22float2(v13); accx += f.x; accy += f.y;
      f = __half22float2(v14); accx += f.x; accy += f.y;
      f = __half22float2(v15); accx += f.x; accy += f.y;
    }
    for (; j + 8 <= cnt; j += 8) {
      const __half2* q0 = reinterpret_cast<const __half2*>(gb + (long)__shfl(cid, j + 0));
      const __half2* q1 = reinterpret_cast<const __half2*>(gb + (long)__shfl(cid, j + 1));
      const __half2* q2 = reinterpret_cast<const __half2*>(gb + (long)__shfl(cid, j + 2));
      const __half2* q3 = reinterpret_cast<const __half2*>(gb + (long)__shfl(cid, j + 3));
      const __half2* q4 = reinterpret_cast<const __half2*>(gb + (long)__shfl(cid, j + 4));
      const __half2* q5 = reinterpret_cast<const __half2*>(gb + (long)__shfl(cid, j + 5));
      const __half2* q6 = reinterpret_cast<const __half2*>(gb + (long)__shfl(cid, j + 6));
      const __half2* q7 = reinterpret_cast<const __half2*>(gb + (long)__shfl(cid, j + 7));
      __half2 v0 = q0[cl], v1 = q1[cl], v2 = q2[cl], v3 = q3[cl];
      __half2 v4 = q4[cl], v5 = q5[cl], v6 = q6[cl], v7 = q7[cl];
      float2 f;
      f = __half22float2(v0); accx += f.x; accy += f.y;
      f = __half22float2(v1); accx += f.x; accy += f.y;
      f = __half22float2(v2); accx += f.x; accy += f.y;
      f = __half22float2(v3); accx += f.x; accy += f.y;
      f = __half22float2(v4); accx += f.x; accy += f.y;
      f = __half22float2(v5); accx += f.x; accy += f.y;
      f = __half22float2(v6); accx += f.x; accy += f.y;
      f = __half22float2(v7); accx += f.x; accy += f.y;
    }
    for (; j < cnt; j++) {
      const __half2* p = reinterpret_cast<const __half2*>(gb + (long)__shfl(cid, j));
      float2 f = __half22float2(p[cl]);
      accx += f.x; accy += f.y;
    }
    e += 64;
  }
  if (lane < 48) {
    float dv = dinv[d];
    float2 bb = *reinterpret_cast<const float2*>(&bias[2 * lane]);
    float v0 = fmaxf(fmaf(accx, dv, bb.x), 0.f);
    float v1 = fmaxf(fmaf(accy, dv, bb.y), 0.f);
    *reinterpret_cast<float2*>(&hout[(long)d * HD + 2 * lane]) = make_float2(v0, v1);
  }
}

// ---------------- pooling: one block per graph, contiguous rows, NO atomics ----------------
// 240 active threads = 24 float4-col-groups x 10 node-substreams; LDS reduce.
__global__ __launch_bounds__(256) void pool3_k(const float* __restrict__ hA,
                                               const float* __restrict__ hB,
                                               const float* __restrict__ hC,
                                               const int* __restrict__ gstart,
                                               float* __restrict__ P) {
  __shared__ float red[240][12];
  const int g = blockIdx.x;
  const int t = threadIdx.x;
  const int q = t % 24, s = t / 24;
  const int n0 = gstart[g], n1 = gstart[g + 1];
  if (t < 240) {
    float4 aA = make_float4(0.f, 0.f, 0.f, 0.f), aB = aA, aC = aA;
    for (int n = n0 + s; n < n1; n += 10) {
      float4 v;
      v = *reinterpret_cast<const float4*>(&hA[(long)n * HD + 4 * q]);
      aA.x += v.x; aA.y += v.y; aA.z += v.z; aA.w += v.w;
      v = *reinterpret_cast<const float4*>(&hB[(long)n * HD + 4 * q]);
      aB.x += v.x; aB.y += v.y; aB.z += v.z; aB.w += v.w;
      v = *reinterpret_cast<const float4*>(&hC[(long)n * HD + 4 * q]);
      aC.x += v.x; aC.y += v.y; aC.z += v.z; aC.w += v.w;
    }
    red[t][0] = aA.x; red[t][1] = aA.y; red[t][2]  = aA.z; red[t][3]  = aA.w;
    red[t][4] = aB.x; red[t][5] = aB.y; red[t][6]  = aB.z; red[t][7]  = aB.w;
    red[t][8] = aC.x; red[t][9] = aC.y; red[t][10] = aC.z; red[t][11] = aC.w;
  }
  __syncthreads();
  if (t < 24) {
    float sum[12];
#pragma unroll
    for (int c = 0; c < 12; c++) sum[c] = 0.f;
    for (int ss = 0; ss < 10; ss++)
#pragma unroll
      for (int c = 0; c < 12; c++) sum[c] += red[ss * 24 + t][c];
#pragma unroll
    for (int k = 0; k < 4; k++) {
      P[0 * NG * HD + g * HD + 4 * t + k] = sum[k];
      P[1 * NG * HD + g * HD + 4 * t + k] = sum[4 + k];
      P[2 * NG * HD + g * HD + 4 * t + k] = sum[8 + k];
    }
  }
}

// ---------------- tiny dense tail: JK-proj on pooled sums + MLP ----------------

__global__ void emb_k(const float* __restrict__ P, const int* __restrict__ gstart,
                      const float* __restrict__ Wjk, const float* __restrict__ bjk,
                      float* __restrict__ emb) {
  int idx = blockIdx.x * 256 + threadIdx.x;
  if (idx >= NG * HD) return;
  int gr = idx / HD, c = idx - gr * HD;
  const float* p1 = P + (long)gr * HD;
  const float* p2 = p1 + (long)NG * HD;
  const float* p3 = p2 + (long)NG * HD;
  float acc = (float)(gstart[gr + 1] - gstart[gr]) * bjk[c];
  for (int k = 0; k < HD; k++) {
    acc = fmaf(p1[k], Wjk[k * HD + c], acc);
    acc = fmaf(p2[k], Wjk[(HD + k) * HD + c], acc);
    acc = fmaf(p3[k], Wjk[(2 * HD + k) * HD + c], acc);
  }
  emb[idx] = acc;
}

__global__ void mlp1_k(const float* __restrict__ emb, const float* __restrict__ W,
                       const float* __restrict__ b, float* __restrict__ hid) {
  int idx = blockIdx.x * 256 + threadIdx.x;
  if (idx >= NG * HD) return;
  int gr = idx / HD, c = idx - gr * HD;
  const float* e = emb + (long)gr * HD;
  float acc = b[c];
  for (int k = 0; k < HD; k++) acc = fmaf(e[k], W[k * HD + c], acc);
  hid[idx] = fmaxf(acc, 0.f);
}

__global__ void mlp2_k(const float* __restrict__ hid, const float* __restrict__ W,
                       const float* __restrict__ b, float* __restrict__ out) {
  int idx = blockIdx.x * 256 + threadIdx.x;
  if (idx >= NG * OD) return;
  int gr = idx / OD, c = idx - gr * OD;
  const float* h = hid + (long)gr * HD;
  float acc = b[c];
  for (int k = 0; k < HD; k++) acc = fmaf(h[k], W[k * OD + c], acc);
  out[idx] = acc;
}

// ---------------- launch ----------------

extern "C" void kernel_launch(void* const* d_in, const int* in_sizes, int n_in,
                              void* d_out, int out_size, void* d_ws, size_t ws_size,
                              hipStream_t stream) {
  const float* x = (const float*)d_in[0];
  const int* ei = (const int*)d_in[1];
  const int* batch = (const int*)d_in[2];
  const float* W0 = (const float*)d_in[3];  const float* b0 = (const float*)d_in[4];
  const float* W1 = (const float*)d_in[5];  const float* b1 = (const float*)d_in[6];
  const float* W2 = (const float*)d_in[7];  const float* b2 = (const float*)d_in[8];
  const float* Wjk = (const float*)d_in[9]; const float* bjk = (const float*)d_in[10];
  const float* Wm1 = (const float*)d_in[11]; const float* bm1 = (const float*)d_in[12];
  const float* Wm2 = (const float*)d_in[13]; const float* bm2 = (const float*)d_in[14];
  const int* srcp = ei;
  const int* dstp = ei + NE;

  char* wp = (char*)d_ws;
  size_t off = 0;
  auto alloc = [&](size_t bytes) -> void* {
    void* p = wp + off;
    off += bytes;
    off = (off + 255) & ~(size_t)255;
    return p;
  };
  int* cnt    = (int*)alloc((size_t)NN * 4);
  int* rowp   = (int*)alloc((size_t)(NN + 1) * 4);
  int* rank   = (int*)alloc((size_t)NE * 4);
  int* colb   = (int*)alloc((size_t)NE * 4);
  float* dinv = (float*)alloc((size_t)NN * 4);
  int* gstart = (int*)alloc((size_t)(NG + 1) * 4);
  int* bsum   = (int*)alloc((size_t)SCAN_BLOCKS * 4);
  int* boff   = (int*)alloc((size_t)SCAN_BLOCKS * 4);
  __half* g   = (__half*)alloc((size_t)NN * HD * 2);
  float* hA   = (float*)alloc((size_t)NN * HD * 4);
  float* hB   = (float*)alloc((size_t)NN * HD * 4);
  float* hC   = (float*)alloc((size_t)NN * HD * 4);
  float* P    = (float*)alloc((size_t)3 * NG * HD * 4);
  float* emb  = (float*)alloc((size_t)NG * HD * 4);
  float* hid  = (float*)alloc((size_t)NG * HD * 4);

  // zero CSR counters (must happen every call — harness does not re-poison)
  zero_k<<<(NN + 255) / 256, 256, 0, stream>>>(cnt);

  // CSR build + degrees + graph offsets
  const int eb8 = (NE / 8 + 255) / 256;  // 8 edges per thread
  hist_k<<<eb8, 256, 0, stream>>>(dstp, cnt, rank);
  gstart_k<<<(NN + 255) / 256, 256, 0, stream>>>(batch, gstart);
  scan_part_k<<<SCAN_BLOCKS, 256, 0, stream>>>(cnt, bsum, dinv);
  scan_top_k<<<1, 64, 0, stream>>>(bsum, boff, rowp);
  scan_fin_k<<<SCAN_BLOCKS, 256, 0, stream>>>(cnt, boff, rowp);
  fill_k<<<eb8, 256, 0, stream>>>(srcp, dstp, rowp, rank, colb);

  const int gemm_grid = (NN + 127) / 128;
  const int gath_grid = (NN + 3) / 4;
  // layer 1: x[50000,128] -> hA
  gemm_scale_k<IND><<<gemm_grid, 192, 0, stream>>>(x, W0, dinv, g);
  gather_k<<<gath_grid, 256, 0, stream>>>(g, rowp, colb, dinv, b0, hA);
  // layer 2: hA -> hB
  gemm_scale_k<HD><<<gemm_grid, 192, 0, stream>>>(hA, W1, dinv, g);
  gather_k<<<gath_grid, 256, 0, stream>>>(g, rowp, colb, dinv, b1, hB);
  // layer 3: hB -> hC
  gemm_scale_k<HD><<<gemm_grid, 192, 0, stream>>>(hB, W2, dinv, g);
  gather_k<<<gath_grid, 256, 0, stream>>>(g, rowp, colb, dinv, b2, hC);

  // pooling (one block per graph, contiguous ranges, no atomics)
  pool3_k<<<NG, 256, 0, stream>>>(hA, hB, hC, gstart, P);

  // JK cat + lin on pooled sums (linearity of pooling), then MLP head
  emb_k<<<(NG * HD + 255) / 256, 256, 0, stream>>>(P, gstart, Wjk, bjk, emb);
  mlp1_k<<<(NG * HD + 255) / 256, 256, 0, stream>>>(emb, Wm1, bm1, hid);
  mlp2_k<<<(NG * OD + 255) / 256, 256, 0, stream>>>(hid, Wm2, bm2, (float*)d_out);
}

// Round 8
// 262.353 us; speedup vs baseline: 1.5172x; 1.0671x over previous
//
#include <hip/hip_runtime.h>
#include <hip/hip_fp16.h>

#define NN 50000
#define NE 800000
#define NG 500
#define IND 128
#define HD 96
#define OD 64

#define SCAN_CHUNK 2048
#define SCAN_BLOCKS ((NN + SCAN_CHUNK - 1) / SCAN_CHUNK)  // 25

// ---------------- CSR build ----------------

__global__ void zero_k(int* __restrict__ cnt) {
  int i = blockIdx.x * 256 + threadIdx.x;
  if (i < NN) cnt[i] = 0;
}

// histogram + within-node rank in one pass (8 edges/thread, independent chains)
__global__ void hist_k(const int* __restrict__ dst, int* __restrict__ cnt,
                       int* __restrict__ rank) {
  int i0 = (blockIdx.x * 256 + threadIdx.x) * 8;
  if (i0 + 8 <= NE) {
    int4 d0 = *reinterpret_cast<const int4*>(&dst[i0]);
    int4 d1 = *reinterpret_cast<const int4*>(&dst[i0 + 4]);
    int4 r0, r1;
    r0.x = atomicAdd(&cnt[d0.x], 1);
    r0.y = atomicAdd(&cnt[d0.y], 1);
    r0.z = atomicAdd(&cnt[d0.z], 1);
    r0.w = atomicAdd(&cnt[d0.w], 1);
    r1.x = atomicAdd(&cnt[d1.x], 1);
    r1.y = atomicAdd(&cnt[d1.y], 1);
    r1.z = atomicAdd(&cnt[d1.z], 1);
    r1.w = atomicAdd(&cnt[d1.w], 1);
    *reinterpret_cast<int4*>(&rank[i0]) = r0;
    *reinterpret_cast<int4*>(&rank[i0 + 4]) = r1;
  } else {
    for (int i = i0; i < NE; i++) rank[i] = atomicAdd(&cnt[dst[i]], 1);
  }
}

// graph start offsets from sorted batch (boundary detection, no atomics)
__global__ void gstart_k(const int* __restrict__ batch, int* __restrict__ gstart) {
  int n = blockIdx.x * 256 + threadIdx.x;
  if (n >= NN) return;
  if (n == 0) {
    for (int g = 0; g <= batch[0]; g++) gstart[g] = 0;
    for (int g = batch[NN - 1] + 1; g <= NG; g++) gstart[g] = NN;
  } else {
    int b0 = batch[n - 1], b1 = batch[n];
    for (int g = b0 + 1; g <= b1; g++) gstart[g] = n;
  }
}

// phase 1: per-block partial sums over 2048-elem chunks; also dinv = rsqrt(deg+1)
__global__ __launch_bounds__(256) void scan_part_k(const int* __restrict__ cnt,
                                                   int* __restrict__ bsum,
                                                   float* __restrict__ dinv) {
  __shared__ int ts[256];
  const int tid = threadIdx.x;
  const int base = blockIdx.x * SCAN_CHUNK + tid * 8;
  int s = 0;
#pragma unroll
  for (int j = 0; j < 8; j++) {
    int idx = base + j;
    if (idx < NN) {
      int c = cnt[idx];
      s += c;
      dinv[idx] = rsqrtf((float)(c + 1));
    }
  }
  ts[tid] = s;
  __syncthreads();
  for (int off = 128; off > 0; off >>= 1) {
    if (tid < off) ts[tid] += ts[tid + off];
    __syncthreads();
  }
  if (tid == 0) bsum[blockIdx.x] = ts[0];
}

// phase 2: one wave scans the 25 block sums -> exclusive boff; row_ptr[NN]=NE
__global__ __launch_bounds__(64) void scan_top_k(const int* __restrict__ bsum,
                                                 int* __restrict__ boff,
                                                 int* __restrict__ row_ptr) {
  int tid = threadIdx.x;
  int v = (tid < SCAN_BLOCKS) ? bsum[tid] : 0;
  for (int off = 1; off < 64; off <<= 1) {
    int u = __shfl_up(v, off);
    if (tid >= off) v += u;
  }
  if (tid < SCAN_BLOCKS) boff[tid] = v - bsum[tid];  // exclusive
  if (tid == 0) row_ptr[NN] = NE;
}

// phase 3: per-block local exclusive scan + block offset -> row_ptr
__global__ __launch_bounds__(256) void scan_fin_k(const int* __restrict__ cnt,
                                                  const int* __restrict__ boff,
                                                  int* __restrict__ row_ptr) {
  __shared__ int ts[256];
  const int tid = threadIdx.x;
  const int base = blockIdx.x * SCAN_CHUNK + tid * 8;
  int v[8];
  int s = 0;
#pragma unroll
  for (int j = 0; j < 8; j++) {
    int idx = base + j;
    v[j] = (idx < NN) ? cnt[idx] : 0;
    s += v[j];
  }
  ts[tid] = s;
  __syncthreads();
  for (int off = 1; off < 256; off <<= 1) {
    int t = (tid >= off) ? ts[tid - off] : 0;
    __syncthreads();
    ts[tid] += t;
    __syncthreads();
  }
  int run = ((tid == 0) ? 0 : ts[tid - 1]) + boff[blockIdx.x];
#pragma unroll
  for (int j = 0; j < 8; j++) {
    int idx = base + j;
    if (idx < NN) row_ptr[idx] = run;
    run += v[j];
  }
}

// atomic-free scatter: col[rowp[d]+rank] = src byte-offset (8 edges/thread)
__global__ void fill_k(const int* __restrict__ src, const int* __restrict__ dst,
                       const int* __restrict__ row_ptr, const int* __restrict__ rank,
                       int* __restrict__ col) {
  int i0 = (blockIdx.x * 256 + threadIdx.x) * 8;
  if (i0 + 8 <= NE) {
    int4 d0 = *reinterpret_cast<const int4*>(&dst[i0]);
    int4 d1 = *reinterpret_cast<const int4*>(&dst[i0 + 4]);
    int4 s0 = *reinterpret_cast<const int4*>(&src[i0]);
    int4 s1 = *reinterpret_cast<const int4*>(&src[i0 + 4]);
    int4 r0 = *reinterpret_cast<const int4*>(&rank[i0]);
    int4 r1 = *reinterpret_cast<const int4*>(&rank[i0 + 4]);
    int p0 = row_ptr[d0.x], p1 = row_ptr[d0.y], p2 = row_ptr[d0.z], p3 = row_ptr[d0.w];
    int p4 = row_ptr[d1.x], p5 = row_ptr[d1.y], p6 = row_ptr[d1.z], p7 = row_ptr[d1.w];
    col[p0 + r0.x] = s0.x * (HD * 2);
    col[p1 + r0.y] = s0.y * (HD * 2);
    col[p2 + r0.z] = s0.z * (HD * 2);
    col[p3 + r0.w] = s0.w * (HD * 2);
    col[p4 + r1.x] = s1.x * (HD * 2);
    col[p5 + r1.y] = s1.y * (HD * 2);
    col[p6 + r1.z] = s1.z * (HD * 2);
    col[p7 + r1.w] = s1.w * (HD * 2);
  } else {
    for (int i = i0; i < NE; i++)
      col[row_ptr[dst[i]] + rank[i]] = src[i] * (HD * 2);
  }
}

// ---------------- g = fp16((h @ W) * dinv[:,None]) ----------------
// BM=64, BN=96, BK=32, 256 threads = 32 rowg x 8 colg; thread = 2 rows x 12 cols.
// A staged transposed, stride 66: staging writes 2-way (free), reads conflict-free.
// Grid = 782 blocks -> ~3 blocks/CU x 4 waves = ~12 waves/CU.
template <int K>
__global__ __launch_bounds__(256) void gemm_scale_k(const float* __restrict__ h,
                                                    const float* __restrict__ W,
                                                    const float* __restrict__ dinv,
                                                    __half* __restrict__ g) {
  __shared__ float hsT[32][66];                                // [k][row], 264B stride
  __shared__ __attribute__((aligned(16))) float ws[32][100];   // [k][col], 400B stride
  const int tid = threadIdx.x;
  const int rowg = tid >> 3;   // 0..31
  const int colg = tid & 7;    // 0..7
  const int row0 = blockIdx.x * 64;

  float acc[2][12];
#pragma unroll
  for (int i = 0; i < 2; i++)
#pragma unroll
    for (int j = 0; j < 12; j++) acc[i][j] = 0.f;

  for (int k0 = 0; k0 < K; k0 += 32) {
    // stage A transposed: 64 rows x 8 k-quads = 512 float4 loads (2 iters)
#pragma unroll
    for (int lin = tid; lin < 512; lin += 256) {
      int r = lin >> 3, q = lin & 7;
      int grow = row0 + r;
      float4 v = make_float4(0.f, 0.f, 0.f, 0.f);
      if (grow < NN) v = *reinterpret_cast<const float4*>(&h[(long)grow * K + k0 + 4 * q]);
      hsT[4 * q + 0][r] = v.x;
      hsT[4 * q + 1][r] = v.y;
      hsT[4 * q + 2][r] = v.z;
      hsT[4 * q + 3][r] = v.w;
    }
    // stage W: 32 k x 24 float4 = 768 (3 iters)
#pragma unroll
    for (int lin = tid; lin < 768; lin += 256) {
      int kk = lin / 24, c4 = lin - kk * 24;
      *reinterpret_cast<float4*>(&ws[kk][4 * c4]) =
          *reinterpret_cast<const float4*>(&W[(long)(k0 + kk) * HD + 4 * c4]);
    }
    __syncthreads();
#pragma unroll 8
    for (int k = 0; k < 32; k++) {
      float2 a = *reinterpret_cast<const float2*>(&hsT[k][2 * rowg]);
      float4 w0 = *reinterpret_cast<const float4*>(&ws[k][12 * colg]);
      float4 w1 = *reinterpret_cast<const float4*>(&ws[k][12 * colg + 4]);
      float4 w2 = *reinterpret_cast<const float4*>(&ws[k][12 * colg + 8]);
      float wv[12] = {w0.x, w0.y, w0.z, w0.w, w1.x, w1.y, w1.z, w1.w,
                      w2.x, w2.y, w2.z, w2.w};
      float av[2] = {a.x, a.y};
#pragma unroll
      for (int i = 0; i < 2; i++)
#pragma unroll
        for (int j = 0; j < 12; j++) acc[i][j] = fmaf(av[i], wv[j], acc[i][j]);
    }
    __syncthreads();
  }
  // epilogue: scale by dinv, pack 12 fp32 -> 6 half2, 3x float2 stores per row
#pragma unroll
  for (int i = 0; i < 2; i++) {
    int row = row0 + 2 * rowg + i;
    if (row < NN) {
      float dv = dinv[row];
      __half2 hh[6];
#pragma unroll
      for (int q = 0; q < 6; q++)
        hh[q] = __floats2half2_rn(acc[i][2 * q] * dv, acc[i][2 * q + 1] * dv);
      __half* go = g + (long)row * HD + 12 * colg;
      *reinterpret_cast<float2*>(go) = *reinterpret_cast<float2*>(&hh[0]);
      *reinterpret_cast<float2*>(go + 4) = *reinterpret_cast<float2*>(&hh[2]);
      *reinterpret_cast<float2*>(go + 8) = *reinterpret_cast<float2*>(&hh[4]);
    }
  }
}

// ---------------- CSR gather (fp16 g) + relu -> hout ----------------
// one wave per node; lane l<48 owns col-pair 2l (one half2 = 4B); lanes 48-63
// mirror lane 0 (same cache line). col[] holds byte offsets. 16/8-edge batches.
__global__ __launch_bounds__(256) void gather_k(const __half* __restrict__ g,
                                                const int* __restrict__ row_ptr,
                                                const int* __restrict__ col,
                                                const float* __restrict__ dinv,
                                                const float* __restrict__ bias,
                                                float* __restrict__ hout) {
  int d = blockIdx.x * 4 + (threadIdx.x >> 6);
  int lane = threadIdx.x & 63;
  if (d >= NN) return;
  const int cl = (lane < 48) ? lane : 0;
  const char* gb = reinterpret_cast<const char*>(g);
  const __half2* gd = reinterpret_cast<const __half2*>(gb + (long)d * (HD * 2));
  float2 fs = __half22float2(gd[cl]);
  float accx = fs.x, accy = fs.y;  // self-loop contribution
  int e = row_ptr[d];
  const int end = row_ptr[d + 1];
  while (e < end) {
    int cnt = end - e; if (cnt > 64) cnt = 64;
    int cid = (lane < cnt) ? col[e + lane] : 0;
    int j = 0;
    for (; j + 16 <= cnt; j += 16) {
      const __half2* p0  = reinterpret_cast<const __half2*>(gb + (long)__shfl(cid, j + 0));
      const __half2* p1  = reinterpret_cast<const __half2*>(gb + (long)__shfl(cid, j + 1));
      const __half2* p2  = reinterpret_cast<const __half2*>(gb + (long)__shfl(cid, j + 2));
      const __half2* p3  = reinterpret_cast<const __half2*>(gb + (long)__shfl(cid, j + 3));
      const __half2* p4  = reinterpret_cast<const __half2*>(gb + (long)__shfl(cid, j + 4));
      const __half2* p5  = reinterpret_cast<const __half2*>(gb + (long)__shfl(cid, j + 5));
      const __half2* p6  = reinterpret_cast<const __half2*>(gb + (long)__shfl(cid, j + 6));
      const __half2* p7  = reinterpret_cast<const __half2*>(gb + (long)__shfl(cid, j + 7));
      const __half2* p8  = reinterpret_cast<const __half2*>(gb + (long)__shfl(cid, j + 8));
      const __half2* p9  = reinterpret_cast<const __half2*>(gb + (long)__shfl(cid, j + 9));
      const __half2* p10 = reinterpret_cast<const __half2*>(gb + (long)__shfl(cid, j + 10));
      const __half2* p11 = reinterpret_cast<const __half2*>(gb + (long)__shfl(cid, j + 11));
      const __half2* p12 = reinterpret_cast<const __half2*>(gb + (long)__shfl(cid, j + 12));
      const __half2* p13 = reinterpret_cast<const __half2*>(gb + (long)__shfl(cid, j + 13));
      const __half2* p14 = reinterpret_cast<const __half2*>(gb + (long)__shfl(cid, j + 14));
      const __half2* p15 = reinterpret_cast<const __half2*>(gb + (long)__shfl(cid, j + 15));
      __half2 v0 = p0[cl],  v1 = p1[cl],  v2 = p2[cl],  v3 = p3[cl];
      __half2 v4 = p4[cl],  v5 = p5[cl],  v6 = p6[cl],  v7 = p7[cl];
      __half2 v8 = p8[cl],  v9 = p9[cl],  v10 = p10[cl], v11 = p11[cl];
      __half2 v12 = p12[cl], v13 = p13[cl], v14 = p14[cl], v15 = p15[cl];
      float2 f;
      f = __half22float2(v0);  accx += f.x; accy += f.y;
      f = __half22float2(v1);  accx += f.x; accy += f.y;
      f = __half22float2(v2);  accx += f.x; accy += f.y;
      f = __half22float2(v3);  accx += f.x; accy += f.y;
      f = __half22float2(v4);  accx += f.x; accy += f.y;
      f = __half22float2(v5);  accx += f.x; accy += f.y;
      f = __half22float2(v6);  accx += f.x; accy += f.y;
      f = __half22float2(v7);  accx += f.x; accy += f.y;
      f = __half22float2(v8);  accx += f.x; accy += f.y;
      f = __half22float2(v9);  accx += f.x; accy += f.y;
      f = __half22float2(v10); accx += f.x; accy += f.y;
      f = __half22float2(v11); accx += f.x; accy += f.y;
      f = __half22float2(v12); accx += f.x; accy += f.y;
      f = __half22float2(v13); accx += f.x; accy += f.y;
      f = __half22float2(v14); accx += f.x; accy += f.y;
      f = __half22float2(v15); accx += f.x; accy += f.y;
    }
    for (; j + 8 <= cnt; j += 8) {
      const __half2* q0 = reinterpret_cast<const __half2*>(gb + (long)__shfl(cid, j + 0));
      const __half2* q1 = reinterpret_cast<const __half2*>(gb + (long)__shfl(cid, j + 1));
      const __half2* q2 = reinterpret_cast<const __half2*>(gb + (long)__shfl(cid, j + 2));
      const __half2* q3 = reinterpret_cast<const __half2*>(gb + (long)__shfl(cid, j + 3));
      const __half2* q4 = reinterpret_cast<const __half2*>(gb + (long)__shfl(cid, j + 4));
      const __half2* q5 = reinterpret_cast<const __half2*>(gb + (long)__shfl(cid, j + 5));
      const __half2* q6 = reinterpret_cast<const __half2*>(gb + (long)__shfl(cid, j + 6));
      const __half2* q7 = reinterpret_cast<const __half2*>(gb + (long)__shfl(cid, j + 7));
      __half2 v0 = q0[cl], v1 = q1[cl], v2 = q2[cl], v3 = q3[cl];
      __half2 v4 = q4[cl], v5 = q5[cl], v6 = q6[cl], v7 = q7[cl];
      float2 f;
      f = __half22float2(v0); accx += f.x; accy += f.y;
      f = __half22float2(v1); accx += f.x; accy += f.y;
      f = __half22float2(v2); accx += f.x; accy += f.y;
      f = __half22float2(v3); accx += f.x; accy += f.y;
      f = __half22float2(v4); accx += f.x; accy += f.y;
      f = __half22float2(v5); accx += f.x; accy += f.y;
      f = __half22float2(v6); accx += f.x; accy += f.y;
      f = __half22float2(v7); accx += f.x; accy += f.y;
    }
    for (; j < cnt; j++) {
      const __half2* p = reinterpret_cast<const __half2*>(gb + (long)__shfl(cid, j));
      float2 f = __half22float2(p[cl]);
      accx += f.x; accy += f.y;
    }
    e += 64;
  }
  if (lane < 48) {
    float dv = dinv[d];
    float2 bb = *reinterpret_cast<const float2*>(&bias[2 * lane]);
    float v0 = fmaxf(fmaf(accx, dv, bb.x), 0.f);
    float v1 = fmaxf(fmaf(accy, dv, bb.y), 0.f);
    *reinterpret_cast<float2*>(&hout[(long)d * HD + 2 * lane]) = make_float2(v0, v1);
  }
}

// ---------------- pooling: one block per graph, contiguous rows, NO atomics ----------------
// 240 active threads = 24 float4-col-groups x 10 node-substreams; LDS reduce.
__global__ __launch_bounds__(256) void pool3_k(const float* __restrict__ hA,
                                               const float* __restrict__ hB,
                                               const float* __restrict__ hC,
                                               const int* __restrict__ gstart,
                                               float* __restrict__ P) {
  __shared__ float red[240][12];
  const int g = blockIdx.x;
  const int t = threadIdx.x;
  const int q = t % 24, s = t / 24;
  const int n0 = gstart[g], n1 = gstart[g + 1];
  if (t < 240) {
    float4 aA = make_float4(0.f, 0.f, 0.f, 0.f), aB = aA, aC = aA;
    for (int n = n0 + s; n < n1; n += 10) {
      float4 v;
      v = *reinterpret_cast<const float4*>(&hA[(long)n * HD + 4 * q]);
      aA.x += v.x; aA.y += v.y; aA.z += v.z; aA.w += v.w;
      v = *reinterpret_cast<const float4*>(&hB[(long)n * HD + 4 * q]);
      aB.x += v.x; aB.y += v.y; aB.z += v.z; aB.w += v.w;
      v = *reinterpret_cast<const float4*>(&hC[(long)n * HD + 4 * q]);
      aC.x += v.x; aC.y += v.y; aC.z += v.z; aC.w += v.w;
    }
    red[t][0] = aA.x; red[t][1] = aA.y; red[t][2]  = aA.z; red[t][3]  = aA.w;
    red[t][4] = aB.x; red[t][5] = aB.y; red[t][6]  = aB.z; red[t][7]  = aB.w;
    red[t][8] = aC.x; red[t][9] = aC.y; red[t][10] = aC.z; red[t][11] = aC.w;
  }
  __syncthreads();
  if (t < 24) {
    float sum[12];
#pragma unroll
    for (int c = 0; c < 12; c++) sum[c] = 0.f;
    for (int ss = 0; ss < 10; ss++)
#pragma unroll
      for (int c = 0; c < 12; c++) sum[c] += red[ss * 24 + t][c];
#pragma unroll
    for (int k = 0; k < 4; k++) {
      P[0 * NG * HD + g * HD + 4 * t + k] = sum[k];
      P[1 * NG * HD + g * HD + 4 * t + k] = sum[4 + k];
      P[2 * NG * HD + g * HD + 4 * t + k] = sum[8 + k];
    }
  }
}

// ---------------- tiny dense tail: JK-proj on pooled sums + MLP ----------------

__global__ void emb_k(const float* __restrict__ P, const int* __restrict__ gstart,
                      const float* __restrict__ Wjk, const float* __restrict__ bjk,
                      float* __restrict__ emb) {
  int idx = blockIdx.x * 256 + threadIdx.x;
  if (idx >= NG * HD) return;
  int gr = idx / HD, c = idx - gr * HD;
  const float* p1 = P + (long)gr * HD;
  const float* p2 = p1 + (long)NG * HD;
  const float* p3 = p2 + (long)NG * HD;
  float acc = (float)(gstart[gr + 1] - gstart[gr]) * bjk[c];
  for (int k = 0; k < HD; k++) {
    acc = fmaf(p1[k], Wjk[k * HD + c], acc);
    acc = fmaf(p2[k], Wjk[(HD + k) * HD + c], acc);
    acc = fmaf(p3[k], Wjk[(2 * HD + k) * HD + c], acc);
  }
  emb[idx] = acc;
}

__global__ void mlp1_k(const float* __restrict__ emb, const float* __restrict__ W,
                       const float* __restrict__ b, float* __restrict__ hid) {
  int idx = blockIdx.x * 256 + threadIdx.x;
  if (idx >= NG * HD) return;
  int gr = idx / HD, c = idx - gr * HD;
  const float* e = emb + (long)gr * HD;
  float acc = b[c];
  for (int k = 0; k < HD; k++) acc = fmaf(e[k], W[k * HD + c], acc);
  hid[idx] = fmaxf(acc, 0.f);
}

__global__ void mlp2_k(const float* __restrict__ hid, const float* __restrict__ W,
                       const float* __restrict__ b, float* __restrict__ out) {
  int idx = blockIdx.x * 256 + threadIdx.x;
  if (idx >= NG * OD) return;
  int gr = idx / OD, c = idx - gr * OD;
  const float* h = hid + (long)gr * HD;
  float acc = b[c];
  for (int k = 0; k < HD; k++) acc = fmaf(h[k], W[k * OD + c], acc);
  out[idx] = acc;
}

// ---------------- launch ----------------

extern "C" void kernel_launch(void* const* d_in, const int* in_sizes, int n_in,
                              void* d_out, int out_size, void* d_ws, size_t ws_size,
                              hipStream_t stream) {
  const float* x = (const float*)d_in[0];
  const int* ei = (const int*)d_in[1];
  const int* batch = (const int*)d_in[2];
  const float* W0 = (const float*)d_in[3];  const float* b0 = (const float*)d_in[4];
  const float* W1 = (const float*)d_in[5];  const float* b1 = (const float*)d_in[6];
  const float* W2 = (const float*)d_in[7];  const float* b2 = (const float*)d_in[8];
  const float* Wjk = (const float*)d_in[9]; const float* bjk = (const float*)d_in[10];
  const float* Wm1 = (const float*)d_in[11]; const float* bm1 = (const float*)d_in[12];
  const float* Wm2 = (const float*)d_in[13]; const float* bm2 = (const float*)d_in[14];
  const int* srcp = ei;
  const int* dstp = ei + NE;

  char* wp = (char*)d_ws;
  size_t off = 0;
  auto alloc = [&](size_t bytes) -> void* {
    void* p = wp + off;
    off += bytes;
    off = (off + 255) & ~(size_t)255;
    return p;
  };
  int* cnt    = (int*)alloc((size_t)NN * 4);
  int* rowp   = (int*)alloc((size_t)(NN + 1) * 4);
  int* rank   = (int*)alloc((size_t)NE * 4);
  int* colb   = (int*)alloc((size_t)NE * 4);
  float* dinv = (float*)alloc((size_t)NN * 4);
  int* gstart = (int*)alloc((size_t)(NG + 1) * 4);
  int* bsum   = (int*)alloc((size_t)SCAN_BLOCKS * 4);
  int* boff   = (int*)alloc((size_t)SCAN_BLOCKS * 4);
  __half* g   = (__half*)alloc((size_t)NN * HD * 2);
  float* hA   = (float*)alloc((size_t)NN * HD * 4);
  float* hB   = (float*)alloc((size_t)NN * HD * 4);
  float* hC   = (float*)alloc((size_t)NN * HD * 4);
  float* P    = (float*)alloc((size_t)3 * NG * HD * 4);
  float* emb  = (float*)alloc((size_t)NG * HD * 4);
  float* hid  = (float*)alloc((size_t)NG * HD * 4);

  // zero CSR counters (must happen every call — harness does not re-poison)
  zero_k<<<(NN + 255) / 256, 256, 0, stream>>>(cnt);

  // CSR build + degrees + graph offsets
  const int eb8 = (NE / 8 + 255) / 256;  // 8 edges per thread
  hist_k<<<eb8, 256, 0, stream>>>(dstp, cnt, rank);
  gstart_k<<<(NN + 255) / 256, 256, 0, stream>>>(batch, gstart);
  scan_part_k<<<SCAN_BLOCKS, 256, 0, stream>>>(cnt, bsum, dinv);
  scan_top_k<<<1, 64, 0, stream>>>(bsum, boff, rowp);
  scan_fin_k<<<SCAN_BLOCKS, 256, 0, stream>>>(cnt, boff, rowp);
  fill_k<<<eb8, 256, 0, stream>>>(srcp, dstp, rowp, rank, colb);

  const int gemm_grid = (NN + 63) / 64;   // 782 blocks
  const int gath_grid = (NN + 3) / 4;
  // layer 1: x[50000,128] -> hA
  gemm_scale_k<IND><<<gemm_grid, 256, 0, stream>>>(x, W0, dinv, g);
  gather_k<<<gath_grid, 256, 0, stream>>>(g, rowp, colb, dinv, b0, hA);
  // layer 2: hA -> hB
  gemm_scale_k<HD><<<gemm_grid, 256, 0, stream>>>(hA, W1, dinv, g);
  gather_k<<<gath_grid, 256, 0, stream>>>(g, rowp, colb, dinv, b1, hB);
  // layer 3: hB -> hC
  gemm_scale_k<HD><<<gemm_grid, 256, 0, stream>>>(hB, W2, dinv, g);
  gather_k<<<gath_grid, 256, 0, stream>>>(g, rowp, colb, dinv, b2, hC);

  // pooling (one block per graph, contiguous ranges, no atomics)
  pool3_k<<<NG, 256, 0, stream>>>(hA, hB, hC, gstart, P);

  // JK cat + lin on pooled sums (linearity of pooling), then MLP head
  emb_k<<<(NG * HD + 255) / 256, 256, 0, stream>>>(P, gstart, Wjk, bjk, emb);
  mlp1_k<<<(NG * HD + 255) / 256, 256, 0, stream>>>(emb, Wm1, bm1, hid);
  mlp2_k<<<(NG * OD + 255) / 256, 256, 0, stream>>>(hid, Wm2, bm2, (float*)d_out);
}

// Round 9
// 251.997 us; speedup vs baseline: 1.5796x; 1.0411x over previous
//
#include <hip/hip_runtime.h>
#include <hip/hip_fp16.h>

#define NN 50000
#define NE 800000
#define NG 500
#define IND 128
#define HD 96
#define OD 64

#define SCAN_CHUNK 2048
#define SCAN_BLOCKS ((NN + SCAN_CHUNK - 1) / SCAN_CHUNK)  // 25

// ---------------- CSR build ----------------

__global__ void zero_k(int* __restrict__ cnt) {
  int i = blockIdx.x * 256 + threadIdx.x;
  if (i < NN) cnt[i] = 0;
}

// histogram + within-node rank in one pass (8 edges/thread, independent chains)
__global__ void hist_k(const int* __restrict__ dst, int* __restrict__ cnt,
                       int* __restrict__ rank) {
  int i0 = (blockIdx.x * 256 + threadIdx.x) * 8;
  if (i0 + 8 <= NE) {
    int4 d0 = *reinterpret_cast<const int4*>(&dst[i0]);
    int4 d1 = *reinterpret_cast<const int4*>(&dst[i0 + 4]);
    int4 r0, r1;
    r0.x = atomicAdd(&cnt[d0.x], 1);
    r0.y = atomicAdd(&cnt[d0.y], 1);
    r0.z = atomicAdd(&cnt[d0.z], 1);
    r0.w = atomicAdd(&cnt[d0.w], 1);
    r1.x = atomicAdd(&cnt[d1.x], 1);
    r1.y = atomicAdd(&cnt[d1.y], 1);
    r1.z = atomicAdd(&cnt[d1.z], 1);
    r1.w = atomicAdd(&cnt[d1.w], 1);
    *reinterpret_cast<int4*>(&rank[i0]) = r0;
    *reinterpret_cast<int4*>(&rank[i0 + 4]) = r1;
  } else {
    for (int i = i0; i < NE; i++) rank[i] = atomicAdd(&cnt[dst[i]], 1);
  }
}

// graph start offsets from sorted batch (boundary detection, no atomics)
__global__ void gstart_k(const int* __restrict__ batch, int* __restrict__ gstart) {
  int n = blockIdx.x * 256 + threadIdx.x;
  if (n >= NN) return;
  if (n == 0) {
    for (int g = 0; g <= batch[0]; g++) gstart[g] = 0;
    for (int g = batch[NN - 1] + 1; g <= NG; g++) gstart[g] = NN;
  } else {
    int b0 = batch[n - 1], b1 = batch[n];
    for (int g = b0 + 1; g <= b1; g++) gstart[g] = n;
  }
}

// phase 1: per-block partial sums over 2048-elem chunks; also dinv = rsqrt(deg+1)
__global__ __launch_bounds__(256) void scan_part_k(const int* __restrict__ cnt,
                                                   int* __restrict__ bsum,
                                                   float* __restrict__ dinv) {
  __shared__ int ts[256];
  const int tid = threadIdx.x;
  const int base = blockIdx.x * SCAN_CHUNK + tid * 8;
  int s = 0;
#pragma unroll
  for (int j = 0; j < 8; j++) {
    int idx = base + j;
    if (idx < NN) {
      int c = cnt[idx];
      s += c;
      dinv[idx] = rsqrtf((float)(c + 1));
    }
  }
  ts[tid] = s;
  __syncthreads();
  for (int off = 128; off > 0; off >>= 1) {
    if (tid < off) ts[tid] += ts[tid + off];
    __syncthreads();
  }
  if (tid == 0) bsum[blockIdx.x] = ts[0];
}

// phase 2: one wave scans the 25 block sums -> exclusive boff; row_ptr[NN]=NE
__global__ __launch_bounds__(64) void scan_top_k(const int* __restrict__ bsum,
                                                 int* __restrict__ boff,
                                                 int* __restrict__ row_ptr) {
  int tid = threadIdx.x;
  int v = (tid < SCAN_BLOCKS) ? bsum[tid] : 0;
  for (int off = 1; off < 64; off <<= 1) {
    int u = __shfl_up(v, off);
    if (tid >= off) v += u;
  }
  if (tid < SCAN_BLOCKS) boff[tid] = v - bsum[tid];  // exclusive
  if (tid == 0) row_ptr[NN] = NE;
}

// phase 3: per-block local exclusive scan + block offset -> row_ptr
__global__ __launch_bounds__(256) void scan_fin_k(const int* __restrict__ cnt,
                                                  const int* __restrict__ boff,
                                                  int* __restrict__ row_ptr) {
  __shared__ int ts[256];
  const int tid = threadIdx.x;
  const int base = blockIdx.x * SCAN_CHUNK + tid * 8;
  int v[8];
  int s = 0;
#pragma unroll
  for (int j = 0; j < 8; j++) {
    int idx = base + j;
    v[j] = (idx < NN) ? cnt[idx] : 0;
    s += v[j];
  }
  ts[tid] = s;
  __syncthreads();
  for (int off = 1; off < 256; off <<= 1) {
    int t = (tid >= off) ? ts[tid - off] : 0;
    __syncthreads();
    ts[tid] += t;
    __syncthreads();
  }
  int run = ((tid == 0) ? 0 : ts[tid - 1]) + boff[blockIdx.x];
#pragma unroll
  for (int j = 0; j < 8; j++) {
    int idx = base + j;
    if (idx < NN) row_ptr[idx] = run;
    run += v[j];
  }
}

// atomic-free scatter: col[rowp[d]+rank] = src byte-offset (8 edges/thread)
__global__ void fill_k(const int* __restrict__ src, const int* __restrict__ dst,
                       const int* __restrict__ row_ptr, const int* __restrict__ rank,
                       int* __restrict__ col) {
  int i0 = (blockIdx.x * 256 + threadIdx.x) * 8;
  if (i0 + 8 <= NE) {
    int4 d0 = *reinterpret_cast<const int4*>(&dst[i0]);
    int4 d1 = *reinterpret_cast<const int4*>(&dst[i0 + 4]);
    int4 s0 = *reinterpret_cast<const int4*>(&src[i0]);
    int4 s1 = *reinterpret_cast<const int4*>(&src[i0 + 4]);
    int4 r0 = *reinterpret_cast<const int4*>(&rank[i0]);
    int4 r1 = *reinterpret_cast<const int4*>(&rank[i0 + 4]);
    int p0 = row_ptr[d0.x], p1 = row_ptr[d0.y], p2 = row_ptr[d0.z], p3 = row_ptr[d0.w];
    int p4 = row_ptr[d1.x], p5 = row_ptr[d1.y], p6 = row_ptr[d1.z], p7 = row_ptr[d1.w];
    col[p0 + r0.x] = s0.x * (HD * 2);
    col[p1 + r0.y] = s0.y * (HD * 2);
    col[p2 + r0.z] = s0.z * (HD * 2);
    col[p3 + r0.w] = s0.w * (HD * 2);
    col[p4 + r1.x] = s1.x * (HD * 2);
    col[p5 + r1.y] = s1.y * (HD * 2);
    col[p6 + r1.z] = s1.z * (HD * 2);
    col[p7 + r1.w] = s1.w * (HD * 2);
  } else {
    for (int i = i0; i < NE; i++)
      col[row_ptr[dst[i]] + rank[i]] = src[i] * (HD * 2);
  }
}

// ---------------- g = fp16((h @ W) * dinv[:,None]) ----------------
// BM=64, BN=96, BK=32, 256 threads = 32 rowg x 8 colg; thread = 2 rows x 12 cols.
// Input h templated: fp32 (layer 1: x) or fp16 (layers 2-3: hA/hB). LDS/accum fp32.
template <int K, typename T>
__global__ __launch_bounds__(256) void gemm_scale_k(const T* __restrict__ h,
                                                    const float* __restrict__ W,
                                                    const float* __restrict__ dinv,
                                                    __half* __restrict__ g) {
  __shared__ float hsT[32][66];                                // [k][row], 264B stride
  __shared__ __attribute__((aligned(16))) float ws[32][100];   // [k][col], 400B stride
  const int tid = threadIdx.x;
  const int rowg = tid >> 3;   // 0..31
  const int colg = tid & 7;    // 0..7
  const int row0 = blockIdx.x * 64;

  float acc[2][12];
#pragma unroll
  for (int i = 0; i < 2; i++)
#pragma unroll
    for (int j = 0; j < 12; j++) acc[i][j] = 0.f;

  for (int k0 = 0; k0 < K; k0 += 32) {
    // stage A transposed into fp32 LDS
    if constexpr (sizeof(T) == 4) {
#pragma unroll
      for (int lin = tid; lin < 512; lin += 256) {
        int r = lin >> 3, q = lin & 7;
        int grow = row0 + r;
        float4 v = make_float4(0.f, 0.f, 0.f, 0.f);
        if (grow < NN)
          v = *reinterpret_cast<const float4*>(&h[(long)grow * K + k0 + 4 * q]);
        hsT[4 * q + 0][r] = v.x;
        hsT[4 * q + 1][r] = v.y;
        hsT[4 * q + 2][r] = v.z;
        hsT[4 * q + 3][r] = v.w;
      }
    } else {
      // fp16 rows: 32 halfs per 32-k chunk = 4 x int4 per row; 64 rows x 4 = 256
      {
        int r = tid >> 2, q = tid & 3;
        int grow = row0 + r;
        if (grow < NN) {
          int4 raw = *reinterpret_cast<const int4*>(
              reinterpret_cast<const __half*>(h) + (long)grow * K + k0 + 8 * q);
          const __half2* hp = reinterpret_cast<const __half2*>(&raw);
#pragma unroll
          for (int t = 0; t < 4; t++) {
            float2 f = __half22float2(hp[t]);
            hsT[8 * q + 2 * t + 0][r] = f.x;
            hsT[8 * q + 2 * t + 1][r] = f.y;
          }
        } else {
#pragma unroll
          for (int t = 0; t < 8; t++) hsT[8 * q + t][r] = 0.f;
        }
      }
    }
    // stage W: 32 k x 24 float4 = 768 (3 iters)
#pragma unroll
    for (int lin = tid; lin < 768; lin += 256) {
      int kk = lin / 24, c4 = lin - kk * 24;
      *reinterpret_cast<float4*>(&ws[kk][4 * c4]) =
          *reinterpret_cast<const float4*>(&W[(long)(k0 + kk) * HD + 4 * c4]);
    }
    __syncthreads();
#pragma unroll 8
    for (int k = 0; k < 32; k++) {
      float2 a = *reinterpret_cast<const float2*>(&hsT[k][2 * rowg]);
      float4 w0 = *reinterpret_cast<const float4*>(&ws[k][12 * colg]);
      float4 w1 = *reinterpret_cast<const float4*>(&ws[k][12 * colg + 4]);
      float4 w2 = *reinterpret_cast<const float4*>(&ws[k][12 * colg + 8]);
      float wv[12] = {w0.x, w0.y, w0.z, w0.w, w1.x, w1.y, w1.z, w1.w,
                      w2.x, w2.y, w2.z, w2.w};
      float av[2] = {a.x, a.y};
#pragma unroll
      for (int i = 0; i < 2; i++)
#pragma unroll
        for (int j = 0; j < 12; j++) acc[i][j] = fmaf(av[i], wv[j], acc[i][j]);
    }
    __syncthreads();
  }
  // epilogue: scale by dinv, pack 12 fp32 -> 6 half2, 3x float2 stores per row
#pragma unroll
  for (int i = 0; i < 2; i++) {
    int row = row0 + 2 * rowg + i;
    if (row < NN) {
      float dv = dinv[row];
      __half2 hh[6];
#pragma unroll
      for (int q = 0; q < 6; q++)
        hh[q] = __floats2half2_rn(acc[i][2 * q] * dv, acc[i][2 * q + 1] * dv);
      __half* go = g + (long)row * HD + 12 * colg;
      *reinterpret_cast<float2*>(go) = *reinterpret_cast<float2*>(&hh[0]);
      *reinterpret_cast<float2*>(go + 4) = *reinterpret_cast<float2*>(&hh[2]);
      *reinterpret_cast<float2*>(go + 8) = *reinterpret_cast<float2*>(&hh[4]);
    }
  }
}

// ---------------- CSR gather (fp16 g) + relu -> fp16 hout ----------------
// one wave per node; 12 lanes per edge (16B float4 = 8 halfs each), 4 edge slots.
// 4-batch unrolled main loop = 16 edges in flight. Cross-slot shfl reduce at end.
// Lanes 48-63 mirror slot0/c0 (same addresses, coalesced away); results discarded.
__global__ __launch_bounds__(256) void gather_k(const __half* __restrict__ g,
                                                const int* __restrict__ row_ptr,
                                                const int* __restrict__ col,
                                                const float* __restrict__ dinv,
                                                const float* __restrict__ bias,
                                                __half* __restrict__ hout) {
  int d = blockIdx.x * 4 + (threadIdx.x >> 6);
  int lane = threadIdx.x & 63;
  if (d >= NN) return;
  const bool active = (lane < 48);
  const int s = active ? (lane / 12) : 0;   // edge slot 0..3
  const int c = active ? (lane % 12) : 0;   // 16B col-quad 0..11
  const int cofs = 16 * c;
  const char* gb = reinterpret_cast<const char*>(g);
  const int own = d * (HD * 2);

  float acc[8];
#pragma unroll
  for (int k = 0; k < 8; k++) acc[k] = 0.f;

  // self-loop: slot 0 only (other slots masked)
  {
    float4 raw = *reinterpret_cast<const float4*>(gb + own + cofs);
    const __half2* hp = reinterpret_cast<const __half2*>(&raw);
    float m = (active && s == 0) ? 1.f : 0.f;
#pragma unroll
    for (int q = 0; q < 4; q++) {
      float2 f = __half22float2(hp[q]);
      acc[2 * q + 0] = fmaf(m, f.x, acc[2 * q + 0]);
      acc[2 * q + 1] = fmaf(m, f.y, acc[2 * q + 1]);
    }
  }

  int e = row_ptr[d];
  const int end = row_ptr[d + 1];
  while (e < end) {
    int cnt = end - e; if (cnt > 64) cnt = 64;
    int cid = (lane < cnt) ? col[e + lane] : own;  // inactive -> own row (valid)
    int j = 0;
    for (; j + 16 <= cnt; j += 16) {
      int o0 = __shfl(cid, j + s);
      int o1 = __shfl(cid, j + 4 + s);
      int o2 = __shfl(cid, j + 8 + s);
      int o3 = __shfl(cid, j + 12 + s);
      float4 r0 = *reinterpret_cast<const float4*>(gb + o0 + cofs);
      float4 r1 = *reinterpret_cast<const float4*>(gb + o1 + cofs);
      float4 r2 = *reinterpret_cast<const float4*>(gb + o2 + cofs);
      float4 r3 = *reinterpret_cast<const float4*>(gb + o3 + cofs);
      const __half2* h0 = reinterpret_cast<const __half2*>(&r0);
      const __half2* h1 = reinterpret_cast<const __half2*>(&r1);
      const __half2* h2 = reinterpret_cast<const __half2*>(&r2);
      const __half2* h3 = reinterpret_cast<const __half2*>(&r3);
#pragma unroll
      for (int q = 0; q < 4; q++) {
        float2 f0 = __half22float2(h0[q]);
        float2 f1 = __half22float2(h1[q]);
        float2 f2 = __half22float2(h2[q]);
        float2 f3 = __half22float2(h3[q]);
        acc[2 * q + 0] += (f0.x + f1.x) + (f2.x + f3.x);
        acc[2 * q + 1] += (f0.y + f1.y) + (f2.y + f3.y);
      }
    }
    for (; j < cnt; j += 4) {
      int o = __shfl(cid, j + s);
      float m = (j + s < cnt) ? 1.f : 0.f;
      float4 r = *reinterpret_cast<const float4*>(gb + o + cofs);
      const __half2* hp = reinterpret_cast<const __half2*>(&r);
#pragma unroll
      for (int q = 0; q < 4; q++) {
        float2 f = __half22float2(hp[q]);
        acc[2 * q + 0] = fmaf(m, f.x, acc[2 * q + 0]);
        acc[2 * q + 1] = fmaf(m, f.y, acc[2 * q + 1]);
      }
    }
    e += 64;
  }

  // cross-slot reduce: slots {2,3} -> {0,1}, then slot1 -> slot0
#pragma unroll
  for (int k = 0; k < 8; k++) acc[k] += __shfl(acc[k], lane + 24);
#pragma unroll
  for (int k = 0; k < 8; k++) acc[k] += __shfl(acc[k], lane + 12);

  if (lane < 12) {
    float dv = dinv[d];
    float4 b0 = *reinterpret_cast<const float4*>(&bias[8 * c]);
    float4 b1 = *reinterpret_cast<const float4*>(&bias[8 * c + 4]);
    float vb[8] = {b0.x, b0.y, b0.z, b0.w, b1.x, b1.y, b1.z, b1.w};
    __half2 hh[4];
#pragma unroll
    for (int q = 0; q < 4; q++) {
      float v0 = fmaxf(fmaf(acc[2 * q + 0], dv, vb[2 * q + 0]), 0.f);
      float v1 = fmaxf(fmaf(acc[2 * q + 1], dv, vb[2 * q + 1]), 0.f);
      hh[q] = __floats2half2_rn(v0, v1);
    }
    *reinterpret_cast<float4*>(&hout[(long)d * HD + 8 * c]) =
        *reinterpret_cast<float4*>(hh);
  }
}

// ---------------- pooling: one block per graph, fp16 h, NO atomics ----------------
// 240 active threads = 24 col-groups (4 halfs = 8B) x 10 node-substreams; LDS reduce.
__global__ __launch_bounds__(256) void pool3_k(const __half* __restrict__ hA,
                                               const __half* __restrict__ hB,
                                               const __half* __restrict__ hC,
                                               const int* __restrict__ gstart,
                                               float* __restrict__ P) {
  __shared__ float red[240][12];
  const int g = blockIdx.x;
  const int t = threadIdx.x;
  const int q = t % 24, s = t / 24;
  const int n0 = gstart[g], n1 = gstart[g + 1];
  if (t < 240) {
    float aA[4] = {0.f, 0.f, 0.f, 0.f}, aB[4] = {0.f, 0.f, 0.f, 0.f},
          aC[4] = {0.f, 0.f, 0.f, 0.f};
    for (int n = n0 + s; n < n1; n += 10) {
      float2 rA = *reinterpret_cast<const float2*>(&hA[(long)n * HD + 4 * q]);
      float2 rB = *reinterpret_cast<const float2*>(&hB[(long)n * HD + 4 * q]);
      float2 rC = *reinterpret_cast<const float2*>(&hC[(long)n * HD + 4 * q]);
      const __half2* pA = reinterpret_cast<const __half2*>(&rA);
      const __half2* pB = reinterpret_cast<const __half2*>(&rB);
      const __half2* pC = reinterpret_cast<const __half2*>(&rC);
#pragma unroll
      for (int u = 0; u < 2; u++) {
        float2 fA = __half22float2(pA[u]);
        float2 fB = __half22float2(pB[u]);
        float2 fC = __half22float2(pC[u]);
        aA[2 * u] += fA.x; aA[2 * u + 1] += fA.y;
        aB[2 * u] += fB.x; aB[2 * u + 1] += fB.y;
        aC[2 * u] += fC.x; aC[2 * u + 1] += fC.y;
      }
    }
#pragma unroll
    for (int u = 0; u < 4; u++) {
      red[t][u] = aA[u];
      red[t][4 + u] = aB[u];
      red[t][8 + u] = aC[u];
    }
  }
  __syncthreads();
  if (t < 24) {
    float sum[12];
#pragma unroll
    for (int u = 0; u < 12; u++) sum[u] = 0.f;
    for (int ss = 0; ss < 10; ss++)
#pragma unroll
      for (int u = 0; u < 12; u++) sum[u] += red[ss * 24 + t][u];
#pragma unroll
    for (int k = 0; k < 4; k++) {
      P[0 * NG * HD + g * HD + 4 * t + k] = sum[k];
      P[1 * NG * HD + g * HD + 4 * t + k] = sum[4 + k];
      P[2 * NG * HD + g * HD + 4 * t + k] = sum[8 + k];
    }
  }
}

// ---------------- tiny dense tail: JK-proj on pooled sums + MLP ----------------

__global__ void emb_k(const float* __restrict__ P, const int* __restrict__ gstart,
                      const float* __restrict__ Wjk, const float* __restrict__ bjk,
                      float* __restrict__ emb) {
  int idx = blockIdx.x * 256 + threadIdx.x;
  if (idx >= NG * HD) return;
  int gr = idx / HD, c = idx - gr * HD;
  const float* p1 = P + (long)gr * HD;
  const float* p2 = p1 + (long)NG * HD;
  const float* p3 = p2 + (long)NG * HD;
  float acc = (float)(gstart[gr + 1] - gstart[gr]) * bjk[c];
  for (int k = 0; k < HD; k++) {
    acc = fmaf(p1[k], Wjk[k * HD + c], acc);
    acc = fmaf(p2[k], Wjk[(HD + k) * HD + c], acc);
    acc = fmaf(p3[k], Wjk[(2 * HD + k) * HD + c], acc);
  }
  emb[idx] = acc;
}

__global__ void mlp1_k(const float* __restrict__ emb, const float* __restrict__ W,
                       const float* __restrict__ b, float* __restrict__ hid) {
  int idx = blockIdx.x * 256 + threadIdx.x;
  if (idx >= NG * HD) return;
  int gr = idx / HD, c = idx - gr * HD;
  const float* e = emb + (long)gr * HD;
  float acc = b[c];
  for (int k = 0; k < HD; k++) acc = fmaf(e[k], W[k * HD + c], acc);
  hid[idx] = fmaxf(acc, 0.f);
}

__global__ void mlp2_k(const float* __restrict__ hid, const float* __restrict__ W,
                       const float* __restrict__ b, float* __restrict__ out) {
  int idx = blockIdx.x * 256 + threadIdx.x;
  if (idx >= NG * OD) return;
  int gr = idx / OD, c = idx - gr * OD;
  const float* h = hid + (long)gr * HD;
  float acc = b[c];
  for (int k = 0; k < HD; k++) acc = fmaf(h[k], W[k * OD + c], acc);
  out[idx] = acc;
}

// ---------------- launch ----------------

extern "C" void kernel_launch(void* const* d_in, const int* in_sizes, int n_in,
                              void* d_out, int out_size, void* d_ws, size_t ws_size,
                              hipStream_t stream) {
  const float* x = (const float*)d_in[0];
  const int* ei = (const int*)d_in[1];
  const int* batch = (const int*)d_in[2];
  const float* W0 = (const float*)d_in[3];  const float* b0 = (const float*)d_in[4];
  const float* W1 = (const float*)d_in[5];  const float* b1 = (const float*)d_in[6];
  const float* W2 = (const float*)d_in[7];  const float* b2 = (const float*)d_in[8];
  const float* Wjk = (const float*)d_in[9]; const float* bjk = (const float*)d_in[10];
  const float* Wm1 = (const float*)d_in[11]; const float* bm1 = (const float*)d_in[12];
  const float* Wm2 = (const float*)d_in[13]; const float* bm2 = (const float*)d_in[14];
  const int* srcp = ei;
  const int* dstp = ei + NE;

  char* wp = (char*)d_ws;
  size_t off = 0;
  auto alloc = [&](size_t bytes) -> void* {
    void* p = wp + off;
    off += bytes;
    off = (off + 255) & ~(size_t)255;
    return p;
  };
  int* cnt    = (int*)alloc((size_t)NN * 4);
  int* rowp   = (int*)alloc((size_t)(NN + 1) * 4);
  int* rank   = (int*)alloc((size_t)NE * 4);
  int* colb   = (int*)alloc((size_t)NE * 4);
  float* dinv = (float*)alloc((size_t)NN * 4);
  int* gstart = (int*)alloc((size_t)(NG + 1) * 4);
  int* bsum   = (int*)alloc((size_t)SCAN_BLOCKS * 4);
  int* boff   = (int*)alloc((size_t)SCAN_BLOCKS * 4);
  __half* g   = (__half*)alloc((size_t)NN * HD * 2);
  __half* hA  = (__half*)alloc((size_t)NN * HD * 2);
  __half* hB  = (__half*)alloc((size_t)NN * HD * 2);
  __half* hC  = (__half*)alloc((size_t)NN * HD * 2);
  float* P    = (float*)alloc((size_t)3 * NG * HD * 4);
  float* emb  = (float*)alloc((size_t)NG * HD * 4);
  float* hid  = (float*)alloc((size_t)NG * HD * 4);

  // zero CSR counters (must happen every call — harness does not re-poison)
  zero_k<<<(NN + 255) / 256, 256, 0, stream>>>(cnt);

  // CSR build + degrees + graph offsets
  const int eb8 = (NE / 8 + 255) / 256;  // 8 edges per thread
  hist_k<<<eb8, 256, 0, stream>>>(dstp, cnt, rank);
  gstart_k<<<(NN + 255) / 256, 256, 0, stream>>>(batch, gstart);
  scan_part_k<<<SCAN_BLOCKS, 256, 0, stream>>>(cnt, bsum, dinv);
  scan_top_k<<<1, 64, 0, stream>>>(bsum, boff, rowp);
  scan_fin_k<<<SCAN_BLOCKS, 256, 0, stream>>>(cnt, boff, rowp);
  fill_k<<<eb8, 256, 0, stream>>>(srcp, dstp, rowp, rank, colb);

  const int gemm_grid = (NN + 63) / 64;   // 782 blocks
  const int gath_grid = (NN + 3) / 4;
  // layer 1: x[50000,128] (fp32) -> hA (fp16)
  gemm_scale_k<IND, float><<<gemm_grid, 256, 0, stream>>>(x, W0, dinv, g);
  gather_k<<<gath_grid, 256, 0, stream>>>(g, rowp, colb, dinv, b0, hA);
  // layer 2: hA (fp16) -> hB
  gemm_scale_k<HD, __half><<<gemm_grid, 256, 0, stream>>>(hA, W1, dinv, g);
  gather_k<<<gath_grid, 256, 0, stream>>>(g, rowp, colb, dinv, b1, hB);
  // layer 3: hB -> hC
  gemm_scale_k<HD, __half><<<gemm_grid, 256, 0, stream>>>(hB, W2, dinv, g);
  gather_k<<<gath_grid, 256, 0, stream>>>(g, rowp, colb, dinv, b2, hC);

  // pooling (one block per graph, contiguous ranges, no atomics)
  pool3_k<<<NG, 256, 0, stream>>>(hA, hB, hC, gstart, P);

  // JK cat + lin on pooled sums (linearity of pooling), then MLP head
  emb_k<<<(NG * HD + 255) / 256, 256, 0, stream>>>(P, gstart, Wjk, bjk, emb);
  mlp1_k<<<(NG * HD + 255) / 256, 256, 0, stream>>>(emb, Wm1, bm1, hid);
  mlp2_k<<<(NG * OD + 255) / 256, 256, 0, stream>>>(hid, Wm2, bm2, (float*)d_out);
}

// Round 10
// 240.083 us; speedup vs baseline: 1.6580x; 1.0496x over previous
//
#include <hip/hip_runtime.h>
#include <hip/hip_fp16.h>

#define NN 50000
#define NE 800000
#define NG 500
#define IND 128
#define HD 96
#define OD 64

#define SCAN_CHUNK 2048
#define SCAN_BLOCKS ((NN + SCAN_CHUNK - 1) / SCAN_CHUNK)  // 25

// ---------------- CSR build ----------------

__global__ void zero_k(int* __restrict__ cnt) {
  int i = blockIdx.x * 256 + threadIdx.x;
  if (i < NN) cnt[i] = 0;
}

// histogram + within-node rank in one pass (8 edges/thread, independent chains)
__global__ void hist_k(const int* __restrict__ dst, int* __restrict__ cnt,
                       int* __restrict__ rank) {
  int i0 = (blockIdx.x * 256 + threadIdx.x) * 8;
  if (i0 + 8 <= NE) {
    int4 d0 = *reinterpret_cast<const int4*>(&dst[i0]);
    int4 d1 = *reinterpret_cast<const int4*>(&dst[i0 + 4]);
    int4 r0, r1;
    r0.x = atomicAdd(&cnt[d0.x], 1);
    r0.y = atomicAdd(&cnt[d0.y], 1);
    r0.z = atomicAdd(&cnt[d0.z], 1);
    r0.w = atomicAdd(&cnt[d0.w], 1);
    r1.x = atomicAdd(&cnt[d1.x], 1);
    r1.y = atomicAdd(&cnt[d1.y], 1);
    r1.z = atomicAdd(&cnt[d1.z], 1);
    r1.w = atomicAdd(&cnt[d1.w], 1);
    *reinterpret_cast<int4*>(&rank[i0]) = r0;
    *reinterpret_cast<int4*>(&rank[i0 + 4]) = r1;
  } else {
    for (int i = i0; i < NE; i++) rank[i] = atomicAdd(&cnt[dst[i]], 1);
  }
}

// phase 1: per-block partial sums over 2048-elem chunks; also dinv = rsqrt(deg+1)
__global__ __launch_bounds__(256) void scan_part_k(const int* __restrict__ cnt,
                                                   int* __restrict__ bsum,
                                                   float* __restrict__ dinv) {
  __shared__ int ts[256];
  const int tid = threadIdx.x;
  const int base = blockIdx.x * SCAN_CHUNK + tid * 8;
  int s = 0;
#pragma unroll
  for (int j = 0; j < 8; j++) {
    int idx = base + j;
    if (idx < NN) {
      int c = cnt[idx];
      s += c;
      dinv[idx] = rsqrtf((float)(c + 1));
    }
  }
  ts[tid] = s;
  __syncthreads();
  for (int off = 128; off > 0; off >>= 1) {
    if (tid < off) ts[tid] += ts[tid + off];
    __syncthreads();
  }
  if (tid == 0) bsum[blockIdx.x] = ts[0];
}

// phase 2: one wave scans the 25 block sums -> exclusive boff; row_ptr[NN]=NE
__global__ __launch_bounds__(64) void scan_top_k(const int* __restrict__ bsum,
                                                 int* __restrict__ boff,
                                                 int* __restrict__ row_ptr) {
  int tid = threadIdx.x;
  int v = (tid < SCAN_BLOCKS) ? bsum[tid] : 0;
  for (int off = 1; off < 64; off <<= 1) {
    int u = __shfl_up(v, off);
    if (tid >= off) v += u;
  }
  if (tid < SCAN_BLOCKS) boff[tid] = v - bsum[tid];  // exclusive
  if (tid == 0) row_ptr[NN] = NE;
}

// phase 3: per-block local exclusive scan + block offset -> row_ptr
__global__ __launch_bounds__(256) void scan_fin_k(const int* __restrict__ cnt,
                                                  const int* __restrict__ boff,
                                                  int* __restrict__ row_ptr) {
  __shared__ int ts[256];
  const int tid = threadIdx.x;
  const int base = blockIdx.x * SCAN_CHUNK + tid * 8;
  int v[8];
  int s = 0;
#pragma unroll
  for (int j = 0; j < 8; j++) {
    int idx = base + j;
    v[j] = (idx < NN) ? cnt[idx] : 0;
    s += v[j];
  }
  ts[tid] = s;
  __syncthreads();
  for (int off = 1; off < 256; off <<= 1) {
    int t = (tid >= off) ? ts[tid - off] : 0;
    __syncthreads();
    ts[tid] += t;
    __syncthreads();
  }
  int run = ((tid == 0) ? 0 : ts[tid - 1]) + boff[blockIdx.x];
#pragma unroll
  for (int j = 0; j < 8; j++) {
    int idx = base + j;
    if (idx < NN) row_ptr[idx] = run;
    run += v[j];
  }
}

// atomic-free scatter: col[rowp[d]+rank] = src byte-offset (8 edges/thread)
__global__ void fill_k(const int* __restrict__ src, const int* __restrict__ dst,
                       const int* __restrict__ row_ptr, const int* __restrict__ rank,
                       int* __restrict__ col) {
  int i0 = (blockIdx.x * 256 + threadIdx.x) * 8;
  if (i0 + 8 <= NE) {
    int4 d0 = *reinterpret_cast<const int4*>(&dst[i0]);
    int4 d1 = *reinterpret_cast<const int4*>(&dst[i0 + 4]);
    int4 s0 = *reinterpret_cast<const int4*>(&src[i0]);
    int4 s1 = *reinterpret_cast<const int4*>(&src[i0 + 4]);
    int4 r0 = *reinterpret_cast<const int4*>(&rank[i0]);
    int4 r1 = *reinterpret_cast<const int4*>(&rank[i0 + 4]);
    int p0 = row_ptr[d0.x], p1 = row_ptr[d0.y], p2 = row_ptr[d0.z], p3 = row_ptr[d0.w];
    int p4 = row_ptr[d1.x], p5 = row_ptr[d1.y], p6 = row_ptr[d1.z], p7 = row_ptr[d1.w];
    col[p0 + r0.x] = s0.x * (HD * 2);
    col[p1 + r0.y] = s0.y * (HD * 2);
    col[p2 + r0.z] = s0.z * (HD * 2);
    col[p3 + r0.w] = s0.w * (HD * 2);
    col[p4 + r1.x] = s1.x * (HD * 2);
    col[p5 + r1.y] = s1.y * (HD * 2);
    col[p6 + r1.z] = s1.z * (HD * 2);
    col[p7 + r1.w] = s1.w * (HD * 2);
  } else {
    for (int i = i0; i < NE; i++)
      col[row_ptr[dst[i]] + rank[i]] = src[i] * (HD * 2);
  }
}

// ---------------- g = fp16((h @ W) * dinv[:,None]) ----------------
// BM=64, BN=96, BK=32, 256 threads = 32 rowg x 8 colg; thread = 2 rows x 12 cols.
// Input h templated: fp32 (layer 1: x) or fp16 (layers 2-3: hA/hB). LDS/accum fp32.
template <int K, typename T>
__global__ __launch_bounds__(256) void gemm_scale_k(const T* __restrict__ h,
                                                    const float* __restrict__ W,
                                                    const float* __restrict__ dinv,
                                                    __half* __restrict__ g) {
  __shared__ float hsT[32][66];                                // [k][row], 264B stride
  __shared__ __attribute__((aligned(16))) float ws[32][100];   // [k][col], 400B stride
  const int tid = threadIdx.x;
  const int rowg = tid >> 3;   // 0..31
  const int colg = tid & 7;    // 0..7
  const int row0 = blockIdx.x * 64;

  float acc[2][12];
#pragma unroll
  for (int i = 0; i < 2; i++)
#pragma unroll
    for (int j = 0; j < 12; j++) acc[i][j] = 0.f;

  for (int k0 = 0; k0 < K; k0 += 32) {
    if constexpr (sizeof(T) == 4) {
#pragma unroll
      for (int lin = tid; lin < 512; lin += 256) {
        int r = lin >> 3, q = lin & 7;
        int grow = row0 + r;
        float4 v = make_float4(0.f, 0.f, 0.f, 0.f);
        if (grow < NN)
          v = *reinterpret_cast<const float4*>(&h[(long)grow * K + k0 + 4 * q]);
        hsT[4 * q + 0][r] = v.x;
        hsT[4 * q + 1][r] = v.y;
        hsT[4 * q + 2][r] = v.z;
        hsT[4 * q + 3][r] = v.w;
      }
    } else {
      int r = tid >> 2, q = tid & 3;
      int grow = row0 + r;
      if (grow < NN) {
        int4 raw = *reinterpret_cast<const int4*>(
            reinterpret_cast<const __half*>(h) + (long)grow * K + k0 + 8 * q);
        const __half2* hp = reinterpret_cast<const __half2*>(&raw);
#pragma unroll
        for (int t = 0; t < 4; t++) {
          float2 f = __half22float2(hp[t]);
          hsT[8 * q + 2 * t + 0][r] = f.x;
          hsT[8 * q + 2 * t + 1][r] = f.y;
        }
      } else {
#pragma unroll
        for (int t = 0; t < 8; t++) hsT[8 * q + t][r] = 0.f;
      }
    }
#pragma unroll
    for (int lin = tid; lin < 768; lin += 256) {
      int kk = lin / 24, c4 = lin - kk * 24;
      *reinterpret_cast<float4*>(&ws[kk][4 * c4]) =
          *reinterpret_cast<const float4*>(&W[(long)(k0 + kk) * HD + 4 * c4]);
    }
    __syncthreads();
#pragma unroll 8
    for (int k = 0; k < 32; k++) {
      float2 a = *reinterpret_cast<const float2*>(&hsT[k][2 * rowg]);
      float4 w0 = *reinterpret_cast<const float4*>(&ws[k][12 * colg]);
      float4 w1 = *reinterpret_cast<const float4*>(&ws[k][12 * colg + 4]);
      float4 w2 = *reinterpret_cast<const float4*>(&ws[k][12 * colg + 8]);
      float wv[12] = {w0.x, w0.y, w0.z, w0.w, w1.x, w1.y, w1.z, w1.w,
                      w2.x, w2.y, w2.z, w2.w};
      float av[2] = {a.x, a.y};
#pragma unroll
      for (int i = 0; i < 2; i++)
#pragma unroll
        for (int j = 0; j < 12; j++) acc[i][j] = fmaf(av[i], wv[j], acc[i][j]);
    }
    __syncthreads();
  }
#pragma unroll
  for (int i = 0; i < 2; i++) {
    int row = row0 + 2 * rowg + i;
    if (row < NN) {
      float dv = dinv[row];
      __half2 hh[6];
#pragma unroll
      for (int q = 0; q < 6; q++)
        hh[q] = __floats2half2_rn(acc[i][2 * q] * dv, acc[i][2 * q + 1] * dv);
      __half* go = g + (long)row * HD + 12 * colg;
      *reinterpret_cast<float2*>(go) = *reinterpret_cast<float2*>(&hh[0]);
      *reinterpret_cast<float2*>(go + 4) = *reinterpret_cast<float2*>(&hh[2]);
      *reinterpret_cast<float2*>(go + 8) = *reinterpret_cast<float2*>(&hh[4]);
    }
  }
}

// ---------------- CSR gather (fp16 g) + relu -> fp16 hout ----------------
// one wave per node; 12 lanes per edge (16B float4 = 8 halfs each), 4 edge slots.
__global__ __launch_bounds__(256) void gather_k(const __half* __restrict__ g,
                                                const int* __restrict__ row_ptr,
                                                const int* __restrict__ col,
                                                const float* __restrict__ dinv,
                                                const float* __restrict__ bias,
                                                __half* __restrict__ hout) {
  int d = blockIdx.x * 4 + (threadIdx.x >> 6);
  int lane = threadIdx.x & 63;
  if (d >= NN) return;
  const bool active = (lane < 48);
  const int s = active ? (lane / 12) : 0;   // edge slot 0..3
  const int c = active ? (lane % 12) : 0;   // 16B col-quad 0..11
  const int cofs = 16 * c;
  const char* gb = reinterpret_cast<const char*>(g);
  const int own = d * (HD * 2);

  float acc[8];
#pragma unroll
  for (int k = 0; k < 8; k++) acc[k] = 0.f;

  {
    float4 raw = *reinterpret_cast<const float4*>(gb + own + cofs);
    const __half2* hp = reinterpret_cast<const __half2*>(&raw);
    float m = (active && s == 0) ? 1.f : 0.f;
#pragma unroll
    for (int q = 0; q < 4; q++) {
      float2 f = __half22float2(hp[q]);
      acc[2 * q + 0] = fmaf(m, f.x, acc[2 * q + 0]);
      acc[2 * q + 1] = fmaf(m, f.y, acc[2 * q + 1]);
    }
  }

  int e = row_ptr[d];
  const int end = row_ptr[d + 1];
  while (e < end) {
    int cnt = end - e; if (cnt > 64) cnt = 64;
    int cid = (lane < cnt) ? col[e + lane] : own;
    int j = 0;
    for (; j + 16 <= cnt; j += 16) {
      int o0 = __shfl(cid, j + s);
      int o1 = __shfl(cid, j + 4 + s);
      int o2 = __shfl(cid, j + 8 + s);
      int o3 = __shfl(cid, j + 12 + s);
      float4 r0 = *reinterpret_cast<const float4*>(gb + o0 + cofs);
      float4 r1 = *reinterpret_cast<const float4*>(gb + o1 + cofs);
      float4 r2 = *reinterpret_cast<const float4*>(gb + o2 + cofs);
      float4 r3 = *reinterpret_cast<const float4*>(gb + o3 + cofs);
      const __half2* h0 = reinterpret_cast<const __half2*>(&r0);
      const __half2* h1 = reinterpret_cast<const __half2*>(&r1);
      const __half2* h2 = reinterpret_cast<const __half2*>(&r2);
      const __half2* h3 = reinterpret_cast<const __half2*>(&r3);
#pragma unroll
      for (int q = 0; q < 4; q++) {
        float2 f0 = __half22float2(h0[q]);
        float2 f1 = __half22float2(h1[q]);
        float2 f2 = __half22float2(h2[q]);
        float2 f3 = __half22float2(h3[q]);
        acc[2 * q + 0] += (f0.x + f1.x) + (f2.x + f3.x);
        acc[2 * q + 1] += (f0.y + f1.y) + (f2.y + f3.y);
      }
    }
    for (; j < cnt; j += 4) {
      int o = __shfl(cid, j + s);
      float m = (j + s < cnt) ? 1.f : 0.f;
      float4 r = *reinterpret_cast<const float4*>(gb + o + cofs);
      const __half2* hp = reinterpret_cast<const __half2*>(&r);
#pragma unroll
      for (int q = 0; q < 4; q++) {
        float2 f = __half22float2(hp[q]);
        acc[2 * q + 0] = fmaf(m, f.x, acc[2 * q + 0]);
        acc[2 * q + 1] = fmaf(m, f.y, acc[2 * q + 1]);
      }
    }
    e += 64;
  }

#pragma unroll
  for (int k = 0; k < 8; k++) acc[k] += __shfl(acc[k], lane + 24);
#pragma unroll
  for (int k = 0; k < 8; k++) acc[k] += __shfl(acc[k], lane + 12);

  if (lane < 12) {
    float dv = dinv[d];
    float4 b0 = *reinterpret_cast<const float4*>(&bias[8 * c]);
    float4 b1 = *reinterpret_cast<const float4*>(&bias[8 * c + 4]);
    float vb[8] = {b0.x, b0.y, b0.z, b0.w, b1.x, b1.y, b1.z, b1.w};
    __half2 hh[4];
#pragma unroll
    for (int q = 0; q < 4; q++) {
      float v0 = fmaxf(fmaf(acc[2 * q + 0], dv, vb[2 * q + 0]), 0.f);
      float v1 = fmaxf(fmaf(acc[2 * q + 1], dv, vb[2 * q + 1]), 0.f);
      hh[q] = __floats2half2_rn(v0, v1);
    }
    *reinterpret_cast<float4*>(&hout[(long)d * HD + 8 * c]) =
        *reinterpret_cast<float4*>(hh);
  }
}

// ---------------- fused head: pool + JK-proj + MLP, one block per graph ----------------
// Graph boundaries via binary search on sorted batch (no gstart kernel/buffer).
// Pool in LDS (240 threads = 24 col-groups x 10 substreams), then dense tail in-block.
__global__ __launch_bounds__(256) void head_k(const __half* __restrict__ hA,
                                              const __half* __restrict__ hB,
                                              const __half* __restrict__ hC,
                                              const int* __restrict__ batch,
                                              const float* __restrict__ Wjk,
                                              const float* __restrict__ bjk,
                                              const float* __restrict__ Wm1,
                                              const float* __restrict__ bm1,
                                              const float* __restrict__ Wm2,
                                              const float* __restrict__ bm2,
                                              float* __restrict__ out) {
  __shared__ float red[240][12];
  __shared__ float p1[HD], p2[HD], p3[HD], se[HD], shid[HD];
  const int g = blockIdx.x;
  const int t = threadIdx.x;

  // graph range [n0, n1): lower_bound(batch, g), lower_bound(batch, g+1)
  int lo = 0, hi = NN;
  while (lo < hi) { int mid = (lo + hi) >> 1; if (batch[mid] < g) lo = mid + 1; else hi = mid; }
  const int n0 = lo;
  lo = 0; hi = NN;
  while (lo < hi) { int mid = (lo + hi) >> 1; if (batch[mid] < g + 1) lo = mid + 1; else hi = mid; }
  const int n1 = lo;

  // pooling over contiguous node rows
  const int q = t % 24, s = t / 24;
  if (t < 240) {
    float aA[4] = {0.f, 0.f, 0.f, 0.f}, aB[4] = {0.f, 0.f, 0.f, 0.f},
          aC[4] = {0.f, 0.f, 0.f, 0.f};
    for (int n = n0 + s; n < n1; n += 10) {
      float2 rA = *reinterpret_cast<const float2*>(&hA[(long)n * HD + 4 * q]);
      float2 rB = *reinterpret_cast<const float2*>(&hB[(long)n * HD + 4 * q]);
      float2 rC = *reinterpret_cast<const float2*>(&hC[(long)n * HD + 4 * q]);
      const __half2* pA = reinterpret_cast<const __half2*>(&rA);
      const __half2* pB = reinterpret_cast<const __half2*>(&rB);
      const __half2* pC = reinterpret_cast<const __half2*>(&rC);
#pragma unroll
      for (int u = 0; u < 2; u++) {
        float2 fA = __half22float2(pA[u]);
        float2 fB = __half22float2(pB[u]);
        float2 fC = __half22float2(pC[u]);
        aA[2 * u] += fA.x; aA[2 * u + 1] += fA.y;
        aB[2 * u] += fB.x; aB[2 * u + 1] += fB.y;
        aC[2 * u] += fC.x; aC[2 * u + 1] += fC.y;
      }
    }
#pragma unroll
    for (int u = 0; u < 4; u++) {
      red[t][u] = aA[u];
      red[t][4 + u] = aB[u];
      red[t][8 + u] = aC[u];
    }
  }
  __syncthreads();
  if (t < 24) {
    float sum[12];
#pragma unroll
    for (int u = 0; u < 12; u++) sum[u] = 0.f;
    for (int ss = 0; ss < 10; ss++)
#pragma unroll
      for (int u = 0; u < 12; u++) sum[u] += red[ss * 24 + t][u];
#pragma unroll
    for (int k = 0; k < 4; k++) {
      p1[4 * t + k] = sum[k];
      p2[4 * t + k] = sum[4 + k];
      p3[4 * t + k] = sum[8 + k];
    }
  }
  __syncthreads();

  // emb = cnt*bjk + [p1,p2,p3] @ Wjk   (96 threads, coalesced Wjk reads)
  if (t < HD) {
    float acc = (float)(n1 - n0) * bjk[t];
    for (int k = 0; k < HD; k++) {
      acc = fmaf(p1[k], Wjk[k * HD + t], acc);
      acc = fmaf(p2[k], Wjk[(HD + k) * HD + t], acc);
      acc = fmaf(p3[k], Wjk[(2 * HD + k) * HD + t], acc);
    }
    se[t] = acc;
  }
  __syncthreads();
  // hid = relu(emb @ Wm1 + bm1)
  if (t < HD) {
    float acc = bm1[t];
    for (int k = 0; k < HD; k++) acc = fmaf(se[k], Wm1[k * HD + t], acc);
    shid[t] = fmaxf(acc, 0.f);
  }
  __syncthreads();
  // out = hid @ Wm2 + bm2
  if (t < OD) {
    float acc = bm2[t];
    for (int k = 0; k < HD; k++) acc = fmaf(shid[k], Wm2[k * OD + t], acc);
    out[g * OD + t] = acc;
  }
}

// ---------------- launch ----------------

extern "C" void kernel_launch(void* const* d_in, const int* in_sizes, int n_in,
                              void* d_out, int out_size, void* d_ws, size_t ws_size,
                              hipStream_t stream) {
  const float* x = (const float*)d_in[0];
  const int* ei = (const int*)d_in[1];
  const int* batch = (const int*)d_in[2];
  const float* W0 = (const float*)d_in[3];  const float* b0 = (const float*)d_in[4];
  const float* W1 = (const float*)d_in[5];  const float* b1 = (const float*)d_in[6];
  const float* W2 = (const float*)d_in[7];  const float* b2 = (const float*)d_in[8];
  const float* Wjk = (const float*)d_in[9]; const float* bjk = (const float*)d_in[10];
  const float* Wm1 = (const float*)d_in[11]; const float* bm1 = (const float*)d_in[12];
  const float* Wm2 = (const float*)d_in[13]; const float* bm2 = (const float*)d_in[14];
  const int* srcp = ei;
  const int* dstp = ei + NE;

  char* wp = (char*)d_ws;
  size_t off = 0;
  auto alloc = [&](size_t bytes) -> void* {
    void* p = wp + off;
    off += bytes;
    off = (off + 255) & ~(size_t)255;
    return p;
  };
  int* cnt    = (int*)alloc((size_t)NN * 4);
  int* rowp   = (int*)alloc((size_t)(NN + 1) * 4);
  int* rank   = (int*)alloc((size_t)NE * 4);
  int* colb   = (int*)alloc((size_t)NE * 4);
  float* dinv = (float*)alloc((size_t)NN * 4);
  int* bsum   = (int*)alloc((size_t)SCAN_BLOCKS * 4);
  int* boff   = (int*)alloc((size_t)SCAN_BLOCKS * 4);
  __half* g   = (__half*)alloc((size_t)NN * HD * 2);
  __half* hA  = (__half*)alloc((size_t)NN * HD * 2);
  __half* hB  = (__half*)alloc((size_t)NN * HD * 2);
  __half* hC  = (__half*)alloc((size_t)NN * HD * 2);

  // zero CSR counters (must happen every call — harness does not re-poison)
  zero_k<<<(NN + 255) / 256, 256, 0, stream>>>(cnt);

  // CSR build + degrees
  const int eb8 = (NE / 8 + 255) / 256;  // 8 edges per thread
  hist_k<<<eb8, 256, 0, stream>>>(dstp, cnt, rank);
  scan_part_k<<<SCAN_BLOCKS, 256, 0, stream>>>(cnt, bsum, dinv);
  scan_top_k<<<1, 64, 0, stream>>>(bsum, boff, rowp);
  scan_fin_k<<<SCAN_BLOCKS, 256, 0, stream>>>(cnt, boff, rowp);
  fill_k<<<eb8, 256, 0, stream>>>(srcp, dstp, rowp, rank, colb);

  const int gemm_grid = (NN + 63) / 64;   // 782 blocks
  const int gath_grid = (NN + 3) / 4;
  // layer 1: x[50000,128] (fp32) -> hA (fp16)
  gemm_scale_k<IND, float><<<gemm_grid, 256, 0, stream>>>(x, W0, dinv, g);
  gather_k<<<gath_grid, 256, 0, stream>>>(g, rowp, colb, dinv, b0, hA);
  // layer 2: hA (fp16) -> hB
  gemm_scale_k<HD, __half><<<gemm_grid, 256, 0, stream>>>(hA, W1, dinv, g);
  gather_k<<<gath_grid, 256, 0, stream>>>(g, rowp, colb, dinv, b1, hB);
  // layer 3: hB -> hC
  gemm_scale_k<HD, __half><<<gemm_grid, 256, 0, stream>>>(hB, W2, dinv, g);
  gather_k<<<gath_grid, 256, 0, stream>>>(g, rowp, colb, dinv, b2, hC);

  // fused head: pool + JK linear + MLP (one block per graph, boundaries by bsearch)
  head_k<<<NG, 256, 0, stream>>>(hA, hB, hC, batch, Wjk, bjk, Wm1, bm1, Wm2, bm2,
                                 (float*)d_out);
}

// Round 11
// 213.647 us; speedup vs baseline: 1.8631x; 1.1237x over previous
//
#include <hip/hip_runtime.h>
#include <hip/hip_fp16.h>

#define NN 50000
#define NE 800000
#define NG 500
#define IND 128
#define HD 96
#define OD 64

#define SCAN_CHUNK 2048
#define SCAN_BLOCKS ((NN + SCAN_CHUNK - 1) / SCAN_CHUNK)  // 25

typedef _Float16 f16x8 __attribute__((ext_vector_type(8)));
typedef float f32x4 __attribute__((ext_vector_type(4)));

// ---------------- CSR build ----------------

__global__ void zero_k(int* __restrict__ cnt) {
  int i = blockIdx.x * 256 + threadIdx.x;
  if (i < NN) cnt[i] = 0;
}

// histogram + within-node rank in one pass (8 edges/thread, independent chains)
__global__ void hist_k(const int* __restrict__ dst, int* __restrict__ cnt,
                       unsigned short* __restrict__ rank) {
  int i0 = (blockIdx.x * 256 + threadIdx.x) * 8;
  if (i0 + 8 <= NE) {
    int4 d0 = *reinterpret_cast<const int4*>(&dst[i0]);
    int4 d1 = *reinterpret_cast<const int4*>(&dst[i0 + 4]);
    alignas(16) unsigned short r[8];
    r[0] = (unsigned short)atomicAdd(&cnt[d0.x], 1);
    r[1] = (unsigned short)atomicAdd(&cnt[d0.y], 1);
    r[2] = (unsigned short)atomicAdd(&cnt[d0.z], 1);
    r[3] = (unsigned short)atomicAdd(&cnt[d0.w], 1);
    r[4] = (unsigned short)atomicAdd(&cnt[d1.x], 1);
    r[5] = (unsigned short)atomicAdd(&cnt[d1.y], 1);
    r[6] = (unsigned short)atomicAdd(&cnt[d1.z], 1);
    r[7] = (unsigned short)atomicAdd(&cnt[d1.w], 1);
    *reinterpret_cast<int4*>(&rank[i0]) = *reinterpret_cast<int4*>(r);
  } else {
    for (int i = i0; i < NE; i++)
      rank[i] = (unsigned short)atomicAdd(&cnt[dst[i]], 1);
  }
}

// phase 1: per-block partial sums over 2048-elem chunks; also dinv = rsqrt(deg+1)
__global__ __launch_bounds__(256) void scan_part_k(const int* __restrict__ cnt,
                                                   int* __restrict__ bsum,
                                                   float* __restrict__ dinv) {
  __shared__ int ts[256];
  const int tid = threadIdx.x;
  const int base = blockIdx.x * SCAN_CHUNK + tid * 8;
  int s = 0;
#pragma unroll
  for (int j = 0; j < 8; j++) {
    int idx = base + j;
    if (idx < NN) {
      int c = cnt[idx];
      s += c;
      dinv[idx] = rsqrtf((float)(c + 1));
    }
  }
  ts[tid] = s;
  __syncthreads();
  for (int off = 128; off > 0; off >>= 1) {
    if (tid < off) ts[tid] += ts[tid + off];
    __syncthreads();
  }
  if (tid == 0) bsum[blockIdx.x] = ts[0];
}

// phase 2: one wave scans the 25 block sums -> exclusive boff; row_ptr[NN]=NE
__global__ __launch_bounds__(64) void scan_top_k(const int* __restrict__ bsum,
                                                 int* __restrict__ boff,
                                                 int* __restrict__ row_ptr) {
  int tid = threadIdx.x;
  int v = (tid < SCAN_BLOCKS) ? bsum[tid] : 0;
  for (int off = 1; off < 64; off <<= 1) {
    int u = __shfl_up(v, off);
    if (tid >= off) v += u;
  }
  if (tid < SCAN_BLOCKS) boff[tid] = v - bsum[tid];  // exclusive
  if (tid == 0) row_ptr[NN] = NE;
}

// phase 3: per-block local exclusive scan + block offset -> row_ptr
__global__ __launch_bounds__(256) void scan_fin_k(const int* __restrict__ cnt,
                                                  const int* __restrict__ boff,
                                                  int* __restrict__ row_ptr) {
  __shared__ int ts[256];
  const int tid = threadIdx.x;
  const int base = blockIdx.x * SCAN_CHUNK + tid * 8;
  int v[8];
  int s = 0;
#pragma unroll
  for (int j = 0; j < 8; j++) {
    int idx = base + j;
    v[j] = (idx < NN) ? cnt[idx] : 0;
    s += v[j];
  }
  ts[tid] = s;
  __syncthreads();
  for (int off = 1; off < 256; off <<= 1) {
    int t = (tid >= off) ? ts[tid - off] : 0;
    __syncthreads();
    ts[tid] += t;
    __syncthreads();
  }
  int run = ((tid == 0) ? 0 : ts[tid - 1]) + boff[blockIdx.x];
#pragma unroll
  for (int j = 0; j < 8; j++) {
    int idx = base + j;
    if (idx < NN) row_ptr[idx] = run;
    run += v[j];
  }
}

// atomic-free scatter: col[rowp[d]+rank] = src node id (ushort), 8 edges/thread
__global__ void fill_k(const int* __restrict__ src, const int* __restrict__ dst,
                       const int* __restrict__ row_ptr,
                       const unsigned short* __restrict__ rank,
                       unsigned short* __restrict__ col) {
  int i0 = (blockIdx.x * 256 + threadIdx.x) * 8;
  if (i0 + 8 <= NE) {
    int4 d0 = *reinterpret_cast<const int4*>(&dst[i0]);
    int4 d1 = *reinterpret_cast<const int4*>(&dst[i0 + 4]);
    int4 s0 = *reinterpret_cast<const int4*>(&src[i0]);
    int4 s1 = *reinterpret_cast<const int4*>(&src[i0 + 4]);
    alignas(16) unsigned short r[8];
    *reinterpret_cast<int4*>(r) = *reinterpret_cast<const int4*>(&rank[i0]);
    int p0 = row_ptr[d0.x], p1 = row_ptr[d0.y], p2 = row_ptr[d0.z], p3 = row_ptr[d0.w];
    int p4 = row_ptr[d1.x], p5 = row_ptr[d1.y], p6 = row_ptr[d1.z], p7 = row_ptr[d1.w];
    col[p0 + r[0]] = (unsigned short)s0.x;
    col[p1 + r[1]] = (unsigned short)s0.y;
    col[p2 + r[2]] = (unsigned short)s0.z;
    col[p3 + r[3]] = (unsigned short)s0.w;
    col[p4 + r[4]] = (unsigned short)s1.x;
    col[p5 + r[5]] = (unsigned short)s1.y;
    col[p6 + r[6]] = (unsigned short)s1.z;
    col[p7 + r[7]] = (unsigned short)s1.w;
  } else {
    for (int i = i0; i < NE; i++)
      col[row_ptr[dst[i]] + rank[i]] = (unsigned short)src[i];
  }
}

// ---------------- g = fp16((h @ W) * dinv[:,None])  via MFMA f16 ----------------
// 256 threads = 4 waves; wave w owns rows [row0+16w, row0+16w+16) x all 96 cols.
// A fragments direct from global (each element read once); W fp32->f16 packed in
// LDS as [k>>3][col][8] so each B fragment = one 16B ds_read. fp32 MFMA accum.
// mfma_f32_16x16x32_f16 layouts: A[i][k]: i=lane&15, k=8*(lane>>4)+e;
// B[k][j]: j=lane&15, k=8*(lane>>4)+e;  D[i][j]: j=lane&15, i=4*(lane>>4)+e.
template <int K, typename T>
__global__ __launch_bounds__(256) void gemm_scale_k(const T* __restrict__ h,
                                                    const float* __restrict__ W,
                                                    const float* __restrict__ dinv,
                                                    __half* __restrict__ g) {
  __shared__ __attribute__((aligned(16))) _Float16 wpack[K * HD];
  const int tid = threadIdx.x;
  // stage W: fp32 -> f16, packed so B-frag (8 k's for one col) is contiguous
  for (int lin = tid; lin < K * (HD / 4); lin += 256) {
    int k = lin / (HD / 4), n4 = lin - k * (HD / 4);
    float4 v = *reinterpret_cast<const float4*>(&W[(long)k * HD + 4 * n4]);
    int base = (k >> 3) * (HD * 8) + (k & 7);
    wpack[base + (4 * n4 + 0) * 8] = (_Float16)v.x;
    wpack[base + (4 * n4 + 1) * 8] = (_Float16)v.y;
    wpack[base + (4 * n4 + 2) * 8] = (_Float16)v.z;
    wpack[base + (4 * n4 + 3) * 8] = (_Float16)v.w;
  }
  __syncthreads();

  const int lane = tid & 63;
  const int wid = tid >> 6;
  const int r16 = lane & 15;   // A row within tile / D col
  const int kg = lane >> 4;    // k-group 0..3
  const int row_base = blockIdx.x * 64 + wid * 16;
  const int arow = row_base + r16;

  f32x4 acc[6];
#pragma unroll
  for (int t = 0; t < 6; t++) acc[t] = (f32x4){0.f, 0.f, 0.f, 0.f};

#pragma unroll
  for (int kc = 0; kc < K / 32; kc++) {
    // A fragment: row arow, k = kc*32 + kg*8 .. +8
    f16x8 a;
    if (arow < NN) {
      if constexpr (sizeof(T) == 4) {
        const float* ap = h + (long)arow * K + kc * 32 + kg * 8;
        float4 v0 = *reinterpret_cast<const float4*>(ap);
        float4 v1 = *reinterpret_cast<const float4*>(ap + 4);
        a[0] = (_Float16)v0.x; a[1] = (_Float16)v0.y;
        a[2] = (_Float16)v0.z; a[3] = (_Float16)v0.w;
        a[4] = (_Float16)v1.x; a[5] = (_Float16)v1.y;
        a[6] = (_Float16)v1.z; a[7] = (_Float16)v1.w;
      } else {
        a = *reinterpret_cast<const f16x8*>(
            reinterpret_cast<const __half*>(h) + (long)arow * K + kc * 32 + kg * 8);
      }
    } else {
#pragma unroll
      for (int e = 0; e < 8; e++) a[e] = (_Float16)0.f;
    }
#pragma unroll
    for (int t = 0; t < 6; t++) {
      f16x8 b = *reinterpret_cast<const f16x8*>(
          &wpack[(kc * 4 + kg) * (HD * 8) + (t * 16 + r16) * 8]);
      acc[t] = __builtin_amdgcn_mfma_f32_16x16x32_f16(a, b, acc[t], 0, 0, 0);
    }
  }

  // epilogue: D row = row_base + kg*4 + e, col = t*16 + r16; scale + fp16 store
  float dv[4];
  int rb = row_base + kg * 4;
#pragma unroll
  for (int e = 0; e < 4; e++) dv[e] = (rb + e < NN) ? dinv[rb + e] : 0.f;
#pragma unroll
  for (int e = 0; e < 4; e++) {
    int row = rb + e;
    if (row < NN) {
      __half* go = g + (long)row * HD + r16;
#pragma unroll
      for (int t = 0; t < 6; t++) go[t * 16] = __float2half(acc[t][e] * dv[e]);
    }
  }
}

// ---------------- CSR gather (fp16 g) + relu -> fp16 hout ----------------
// one wave per node; 12 lanes per edge (16B float4 = 8 halfs each), 4 edge slots.
__global__ __launch_bounds__(256) void gather_k(const __half* __restrict__ g,
                                                const int* __restrict__ row_ptr,
                                                const unsigned short* __restrict__ col,
                                                const float* __restrict__ dinv,
                                                const float* __restrict__ bias,
                                                __half* __restrict__ hout) {
  int d = blockIdx.x * 4 + (threadIdx.x >> 6);
  int lane = threadIdx.x & 63;
  if (d >= NN) return;
  const bool active = (lane < 48);
  const int s = active ? (lane / 12) : 0;   // edge slot 0..3
  const int c = active ? (lane % 12) : 0;   // 16B col-quad 0..11
  const int cofs = 16 * c;
  const char* gb = reinterpret_cast<const char*>(g);

  float acc[8];
#pragma unroll
  for (int k = 0; k < 8; k++) acc[k] = 0.f;

  {
    float4 raw = *reinterpret_cast<const float4*>(gb + d * (HD * 2) + cofs);
    const __half2* hp = reinterpret_cast<const __half2*>(&raw);
    float m = (active && s == 0) ? 1.f : 0.f;
#pragma unroll
    for (int q = 0; q < 4; q++) {
      float2 f = __half22float2(hp[q]);
      acc[2 * q + 0] = fmaf(m, f.x, acc[2 * q + 0]);
      acc[2 * q + 1] = fmaf(m, f.y, acc[2 * q + 1]);
    }
  }

  int e = row_ptr[d];
  const int end = row_ptr[d + 1];
  while (e < end) {
    int cnt = end - e; if (cnt > 64) cnt = 64;
    int cid = (lane < cnt) ? (int)col[e + lane] : d;  // node id
    int j = 0;
    for (; j + 16 <= cnt; j += 16) {
      int o0 = __shfl(cid, j + s) * (HD * 2);
      int o1 = __shfl(cid, j + 4 + s) * (HD * 2);
      int o2 = __shfl(cid, j + 8 + s) * (HD * 2);
      int o3 = __shfl(cid, j + 12 + s) * (HD * 2);
      float4 r0 = *reinterpret_cast<const float4*>(gb + o0 + cofs);
      float4 r1 = *reinterpret_cast<const float4*>(gb + o1 + cofs);
      float4 r2 = *reinterpret_cast<const float4*>(gb + o2 + cofs);
      float4 r3 = *reinterpret_cast<const float4*>(gb + o3 + cofs);
      const __half2* h0 = reinterpret_cast<const __half2*>(&r0);
      const __half2* h1 = reinterpret_cast<const __half2*>(&r1);
      const __half2* h2 = reinterpret_cast<const __half2*>(&r2);
      const __half2* h3 = reinterpret_cast<const __half2*>(&r3);
#pragma unroll
      for (int q = 0; q < 4; q++) {
        float2 f0 = __half22float2(h0[q]);
        float2 f1 = __half22float2(h1[q]);
        float2 f2 = __half22float2(h2[q]);
        float2 f3 = __half22float2(h3[q]);
        acc[2 * q + 0] += (f0.x + f1.x) + (f2.x + f3.x);
        acc[2 * q + 1] += (f0.y + f1.y) + (f2.y + f3.y);
      }
    }
    for (; j < cnt; j += 4) {
      int o = __shfl(cid, j + s) * (HD * 2);
      float m = (j + s < cnt) ? 1.f : 0.f;
      float4 r = *reinterpret_cast<const float4*>(gb + o + cofs);
      const __half2* hp = reinterpret_cast<const __half2*>(&r);
#pragma unroll
      for (int q = 0; q < 4; q++) {
        float2 f = __half22float2(hp[q]);
        acc[2 * q + 0] = fmaf(m, f.x, acc[2 * q + 0]);
        acc[2 * q + 1] = fmaf(m, f.y, acc[2 * q + 1]);
      }
    }
    e += 64;
  }

#pragma unroll
  for (int k = 0; k < 8; k++) acc[k] += __shfl(acc[k], lane + 24);
#pragma unroll
  for (int k = 0; k < 8; k++) acc[k] += __shfl(acc[k], lane + 12);

  if (lane < 12) {
    float dv = dinv[d];
    float4 b0 = *reinterpret_cast<const float4*>(&bias[8 * c]);
    float4 b1 = *reinterpret_cast<const float4*>(&bias[8 * c + 4]);
    float vb[8] = {b0.x, b0.y, b0.z, b0.w, b1.x, b1.y, b1.z, b1.w};
    __half2 hh[4];
#pragma unroll
    for (int q = 0; q < 4; q++) {
      float v0 = fmaxf(fmaf(acc[2 * q + 0], dv, vb[2 * q + 0]), 0.f);
      float v1 = fmaxf(fmaf(acc[2 * q + 1], dv, vb[2 * q + 1]), 0.f);
      hh[q] = __floats2half2_rn(v0, v1);
    }
    *reinterpret_cast<float4*>(&hout[(long)d * HD + 8 * c]) =
        *reinterpret_cast<float4*>(hh);
  }
}

// ---------------- fused head: pool + JK-proj + MLP, one block per graph ----------------
__global__ __launch_bounds__(256) void head_k(const __half* __restrict__ hA,
                                              const __half* __restrict__ hB,
                                              const __half* __restrict__ hC,
                                              const int* __restrict__ batch,
                                              const float* __restrict__ Wjk,
                                              const float* __restrict__ bjk,
                                              const float* __restrict__ Wm1,
                                              const float* __restrict__ bm1,
                                              const float* __restrict__ Wm2,
                                              const float* __restrict__ bm2,
                                              float* __restrict__ out) {
  __shared__ float red[240][12];
  __shared__ float p1[HD], p2[HD], p3[HD], se[HD], shid[HD];
  const int g = blockIdx.x;
  const int t = threadIdx.x;

  int lo = 0, hi = NN;
  while (lo < hi) { int mid = (lo + hi) >> 1; if (batch[mid] < g) lo = mid + 1; else hi = mid; }
  const int n0 = lo;
  lo = 0; hi = NN;
  while (lo < hi) { int mid = (lo + hi) >> 1; if (batch[mid] < g + 1) lo = mid + 1; else hi = mid; }
  const int n1 = lo;

  const int q = t % 24, s = t / 24;
  if (t < 240) {
    float aA[4] = {0.f, 0.f, 0.f, 0.f}, aB[4] = {0.f, 0.f, 0.f, 0.f},
          aC[4] = {0.f, 0.f, 0.f, 0.f};
    for (int n = n0 + s; n < n1; n += 10) {
      float2 rA = *reinterpret_cast<const float2*>(&hA[(long)n * HD + 4 * q]);
      float2 rB = *reinterpret_cast<const float2*>(&hB[(long)n * HD + 4 * q]);
      float2 rC = *reinterpret_cast<const float2*>(&hC[(long)n * HD + 4 * q]);
      const __half2* pA = reinterpret_cast<const __half2*>(&rA);
      const __half2* pB = reinterpret_cast<const __half2*>(&rB);
      const __half2* pC = reinterpret_cast<const __half2*>(&rC);
#pragma unroll
      for (int u = 0; u < 2; u++) {
        float2 fA = __half22float2(pA[u]);
        float2 fB = __half22float2(pB[u]);
        float2 fC = __half22float2(pC[u]);
        aA[2 * u] += fA.x; aA[2 * u + 1] += fA.y;
        aB[2 * u] += fB.x; aB[2 * u + 1] += fB.y;
        aC[2 * u] += fC.x; aC[2 * u + 1] += fC.y;
      }
    }
#pragma unroll
    for (int u = 0; u < 4; u++) {
      red[t][u] = aA[u];
      red[t][4 + u] = aB[u];
      red[t][8 + u] = aC[u];
    }
  }
  __syncthreads();
  if (t < 24) {
    float sum[12];
#pragma unroll
    for (int u = 0; u < 12; u++) sum[u] = 0.f;
    for (int ss = 0; ss < 10; ss++)
#pragma unroll
      for (int u = 0; u < 12; u++) sum[u] += red[ss * 24 + t][u];
#pragma unroll
    for (int k = 0; k < 4; k++) {
      p1[4 * t + k] = sum[k];
      p2[4 * t + k] = sum[4 + k];
      p3[4 * t + k] = sum[8 + k];
    }
  }
  __syncthreads();

  if (t < HD) {
    float acc = (float)(n1 - n0) * bjk[t];
    for (int k = 0; k < HD; k++) {
      acc = fmaf(p1[k], Wjk[k * HD + t], acc);
      acc = fmaf(p2[k], Wjk[(HD + k) * HD + t], acc);
      acc = fmaf(p3[k], Wjk[(2 * HD + k) * HD + t], acc);
    }
    se[t] = acc;
  }
  __syncthreads();
  if (t < HD) {
    float acc = bm1[t];
    for (int k = 0; k < HD; k++) acc = fmaf(se[k], Wm1[k * HD + t], acc);
    shid[t] = fmaxf(acc, 0.f);
  }
  __syncthreads();
  if (t < OD) {
    float acc = bm2[t];
    for (int k = 0; k < HD; k++) acc = fmaf(shid[k], Wm2[k * OD + t], acc);
    out[g * OD + t] = acc;
  }
}

// ---------------- launch ----------------

extern "C" void kernel_launch(void* const* d_in, const int* in_sizes, int n_in,
                              void* d_out, int out_size, void* d_ws, size_t ws_size,
                              hipStream_t stream) {
  const float* x = (const float*)d_in[0];
  const int* ei = (const int*)d_in[1];
  const int* batch = (const int*)d_in[2];
  const float* W0 = (const float*)d_in[3];  const float* b0 = (const float*)d_in[4];
  const float* W1 = (const float*)d_in[5];  const float* b1 = (const float*)d_in[6];
  const float* W2 = (const float*)d_in[7];  const float* b2 = (const float*)d_in[8];
  const float* Wjk = (const float*)d_in[9]; const float* bjk = (const float*)d_in[10];
  const float* Wm1 = (const float*)d_in[11]; const float* bm1 = (const float*)d_in[12];
  const float* Wm2 = (const float*)d_in[13]; const float* bm2 = (const float*)d_in[14];
  const int* srcp = ei;
  const int* dstp = ei + NE;

  char* wp = (char*)d_ws;
  size_t off = 0;
  auto alloc = [&](size_t bytes) -> void* {
    void* p = wp + off;
    off += bytes;
    off = (off + 255) & ~(size_t)255;
    return p;
  };
  int* cnt    = (int*)alloc((size_t)NN * 4);
  int* rowp   = (int*)alloc((size_t)(NN + 1) * 4);
  unsigned short* rank = (unsigned short*)alloc((size_t)NE * 2);
  unsigned short* colb = (unsigned short*)alloc((size_t)NE * 2);
  float* dinv = (float*)alloc((size_t)NN * 4);
  int* bsum   = (int*)alloc((size_t)SCAN_BLOCKS * 4);
  int* boff   = (int*)alloc((size_t)SCAN_BLOCKS * 4);
  __half* g   = (__half*)alloc((size_t)NN * HD * 2);
  __half* hA  = (__half*)alloc((size_t)NN * HD * 2);
  __half* hB  = (__half*)alloc((size_t)NN * HD * 2);
  __half* hC  = (__half*)alloc((size_t)NN * HD * 2);

  // zero CSR counters (must happen every call — harness does not re-poison)
  zero_k<<<(NN + 255) / 256, 256, 0, stream>>>(cnt);

  // CSR build + degrees
  const int eb8 = (NE / 8 + 255) / 256;  // 8 edges per thread
  hist_k<<<eb8, 256, 0, stream>>>(dstp, cnt, rank);
  scan_part_k<<<SCAN_BLOCKS, 256, 0, stream>>>(cnt, bsum, dinv);
  scan_top_k<<<1, 64, 0, stream>>>(bsum, boff, rowp);
  scan_fin_k<<<SCAN_BLOCKS, 256, 0, stream>>>(cnt, boff, rowp);
  fill_k<<<eb8, 256, 0, stream>>>(srcp, dstp, rowp, rank, colb);

  const int gemm_grid = (NN + 63) / 64;   // 782 blocks
  const int gath_grid = (NN + 3) / 4;
  // layer 1: x[50000,128] (fp32) -> hA (fp16)
  gemm_scale_k<IND, float><<<gemm_grid, 256, 0, stream>>>(x, W0, dinv, g);
  gather_k<<<gath_grid, 256, 0, stream>>>(g, rowp, colb, dinv, b0, hA);
  // layer 2: hA (fp16) -> hB
  gemm_scale_k<HD, __half><<<gemm_grid, 256, 0, stream>>>(hA, W1, dinv, g);
  gather_k<<<gath_grid, 256, 0, stream>>>(g, rowp, colb, dinv, b1, hB);
  // layer 3: hB -> hC
  gemm_scale_k<HD, __half><<<gemm_grid, 256, 0, stream>>>(hB, W2, dinv, g);
  gather_k<<<gath_grid, 256, 0, stream>>>(g, rowp, colb, dinv, b2, hC);

  // fused head: pool + JK linear + MLP (one block per graph, boundaries by bsearch)
  head_k<<<NG, 256, 0, stream>>>(hA, hB, hC, batch, Wjk, bjk, Wm1, bm1, Wm2, bm2,
                                 (float*)d_out);
}